// Round 5
// baseline (5781.883 us; speedup 1.0000x reference)
//
#include <hip/hip_runtime.h>
#include <math.h>

#define NB 256
#define LM 16
#define HID 512
#define H4 2048
#define D2 1024
#define D5 5120
#define NPAIR0 3840   // 256*15
#define ASTR 40       // LDS row stride in shorts (32 data + 8 pad, 80B, 16B-aligned)
#define BSTR 40
#define INC_CAP 512   // max incremental rows (2 per batch)

typedef __attribute__((ext_vector_type(8))) short bf16x8;
typedef __attribute__((ext_vector_type(4))) float f32x4;

__device__ __forceinline__ float sigm(float x) { return 1.0f / (1.0f + expf(-x)); }

__device__ __forceinline__ unsigned short bf16_rne(float f) {
    union { float f; unsigned u; } v; v.f = f;
    unsigned u = v.u;
    return (unsigned short)((u + 0x7fffu + ((u >> 16) & 1u)) >> 16);
}
__device__ __forceinline__ float bf16_tof(unsigned short h) {
    union { unsigned u; float f; } v; v.u = ((unsigned)h) << 16;
    return v.f;
}

struct RegSet { uint4 a0, a1, b0, b1, b2, b3; };

// ---------------------------------------------------------------------------
__global__ __launch_bounds__(256)
void init_kernel(float* ccur, unsigned short* hc_hi, unsigned short* hc_lo,
                 int* pos, int* pair, int4* rowlist0, int* rcount)
{
    int b = blockIdx.x, tid = threadIdx.x;
    for (int u = tid; u < HID; u += 256) {
        ccur[(size_t)b * HID + u] = 0.f;
        ccur[((size_t)NB + b) * HID + u] = 0.f;
        hc_hi[(size_t)b * HID + u] = 0;
        hc_hi[((size_t)NB + b) * HID + u] = 0;
        hc_lo[(size_t)b * HID + u] = 0;
        hc_lo[((size_t)NB + b) * HID + u] = 0;
    }
    if (tid < 16) { pos[b * 16 + tid] = tid; pair[b * 16 + tid] = tid; }
    if (tid < 15) rowlist0[b * 15 + tid] = make_int4(b, tid, tid + 1, tid | (tid << 16));
    if (b == 0 && tid < 16) rcount[tid] = 0;
}

// ---------------------------------------------------------------------------
__global__ __launch_bounds__(256)
void split_w(const float4* __restrict__ w, unsigned short* __restrict__ hi,
             unsigned short* __restrict__ lo, int n4)
{
    for (int i = blockIdx.x * 256 + threadIdx.x; i < n4; i += gridDim.x * 256) {
        float4 f = w[i];
        ushort4 h, l;
        h.x = bf16_rne(f.x); l.x = bf16_rne(f.x - bf16_tof(h.x));
        h.y = bf16_rne(f.y); l.y = bf16_rne(f.y - bf16_tof(h.y));
        h.z = bf16_rne(f.z); l.z = bf16_rne(f.z - bf16_tof(h.z));
        h.w = bf16_rne(f.w); l.w = bf16_rne(f.w - bf16_tof(h.w));
        ((ushort4*)hi)[i] = h;
        ((ushort4*)lo)[i] = l;
    }
}

// ---------------------------------------------------------------------------
__global__ __launch_bounds__(256)
void pack_lstm_w(const float* __restrict__ w_ih_f, const float* __restrict__ w_hh_f,
                 const float* __restrict__ w_ih_b, const float* __restrict__ w_hh_b,
                 unsigned short* __restrict__ wl_hi, unsigned short* __restrict__ wl_lo)
{
    const int total4 = 2 * H4 * 256;
    for (int i = blockIdx.x * 256 + threadIdx.x; i < total4; i += gridDim.x * 256) {
        int k4 = i & 255;
        int j = (i >> 8) & 2047;
        int dir = i >> 19;
        const float* wih = dir ? w_ih_b : w_ih_f;
        const float* whh = dir ? w_hh_b : w_hh_f;
        float4 f = (k4 < 128) ? *(const float4*)(wih + (size_t)j * HID + k4 * 4)
                              : *(const float4*)(whh + (size_t)j * HID + (k4 - 128) * 4);
        ushort4 h, l;
        h.x = bf16_rne(f.x); l.x = bf16_rne(f.x - bf16_tof(h.x));
        h.y = bf16_rne(f.y); l.y = bf16_rne(f.y - bf16_tof(h.y));
        h.z = bf16_rne(f.z); l.z = bf16_rne(f.z - bf16_tof(h.z));
        h.w = bf16_rne(f.w); l.w = bf16_rne(f.w - bf16_tof(h.w));
        ((ushort4*)wl_hi)[i] = h;
        ((ushort4*)wl_lo)[i] = l;
    }
}

// ---------------------------------------------------------------------------
// LSTM step GEMM, bf16x3 MFMA, 2-deep register-prefetch pipeline.
// ---------------------------------------------------------------------------
__global__ __launch_bounds__(256)
void gemm_lstm_mfma(int t, const int* __restrict__ lens,
                    const unsigned short* __restrict__ x_hi, const unsigned short* __restrict__ x_lo,
                    const unsigned short* __restrict__ hc_hi, const unsigned short* __restrict__ hc_lo,
                    const unsigned short* __restrict__ wl_hi, const unsigned short* __restrict__ wl_lo,
                    float* __restrict__ gbuf)
{
    const int col0 = blockIdx.x * 128, row0 = blockIdx.y * 64, dir = blockIdx.z;
    const int tid = threadIdx.x, lane = tid & 63, wid = tid >> 6;
    const int wm = wid >> 1, wn = wid & 1;

    __shared__ __align__(16) unsigned short As[2][64 * ASTR];
    __shared__ __align__(16) unsigned short Bs[2][128 * BSTR];

    const int s_row = tid & 63, s_kp = (tid >> 6) & 1, s_pl = tid >> 7;
    const int b = row0 + s_row;
    const int len = lens[b];
    const int trow = dir ? ((t < len) ? (len - 1 - t) : t) : t;
    const unsigned short* xp = (s_pl ? x_lo : x_hi) + ((size_t)(b * LM + trow)) * HID;
    const unsigned short* hp = (s_pl ? hc_lo : hc_hi) + ((size_t)(dir * NB + b)) * HID;

    const int b_col = (tid & 63) + (((tid >> 6) & 1) << 6), b_kp = tid >> 7;
    const unsigned short* whp = wl_hi + ((size_t)(dir * H4 + col0 + b_col)) * 1024;
    const unsigned short* wlp = wl_lo + ((size_t)(dir * H4 + col0 + b_col)) * 1024;

    auto load_g = [&](RegSet& r, int k0) {
        const unsigned short* asrc = (k0 < HID) ? (xp + k0) : (hp + (k0 - HID));
        r.a0 = *(const uint4*)(asrc + s_kp * 8);
        r.a1 = *(const uint4*)(asrc + s_kp * 8 + 16);
        r.b0 = *(const uint4*)(whp + k0 + b_kp * 8);
        r.b1 = *(const uint4*)(whp + k0 + b_kp * 8 + 16);
        r.b2 = *(const uint4*)(wlp + k0 + b_kp * 8);
        r.b3 = *(const uint4*)(wlp + k0 + b_kp * 8 + 16);
    };
    auto store_l = [&](const RegSet& r) {
        *(uint4*)&As[s_pl][s_row * ASTR + s_kp * 8]      = r.a0;
        *(uint4*)&As[s_pl][s_row * ASTR + s_kp * 8 + 16] = r.a1;
        *(uint4*)&Bs[0][b_col * BSTR + b_kp * 8]      = r.b0;
        *(uint4*)&Bs[0][b_col * BSTR + b_kp * 8 + 16] = r.b1;
        *(uint4*)&Bs[1][b_col * BSTR + b_kp * 8]      = r.b2;
        *(uint4*)&Bs[1][b_col * BSTR + b_kp * 8 + 16] = r.b3;
    };

    f32x4 acc[2][4];
#pragma unroll
    for (int i = 0; i < 2; ++i)
#pragma unroll
        for (int j = 0; j < 4; ++j) acc[i][j] = (f32x4){0.f, 0.f, 0.f, 0.f};

    const int a_off = (wm * 32 + (lane & 15)) * ASTR + (lane >> 4) * 8;
    const int b_off = (wn * 64 + (lane & 15)) * BSTR + (lane >> 4) * 8;

    auto mf = [&]() {
        bf16x8 ah[2], al[2];
#pragma unroll
        for (int fm = 0; fm < 2; ++fm) {
            ah[fm] = *(const bf16x8*)&As[0][a_off + fm * 16 * ASTR];
            al[fm] = *(const bf16x8*)&As[1][a_off + fm * 16 * ASTR];
        }
#pragma unroll
        for (int fn = 0; fn < 4; ++fn) {
            bf16x8 bh = *(const bf16x8*)&Bs[0][b_off + fn * 16 * BSTR];
            bf16x8 bl = *(const bf16x8*)&Bs[1][b_off + fn * 16 * BSTR];
#pragma unroll
            for (int fm = 0; fm < 2; ++fm) {
                acc[fm][fn] = __builtin_amdgcn_mfma_f32_16x16x32_bf16(ah[fm], bh, acc[fm][fn], 0, 0, 0);
                acc[fm][fn] = __builtin_amdgcn_mfma_f32_16x16x32_bf16(ah[fm], bl, acc[fm][fn], 0, 0, 0);
                acc[fm][fn] = __builtin_amdgcn_mfma_f32_16x16x32_bf16(al[fm], bh, acc[fm][fn], 0, 0, 0);
            }
        }
    };

    RegSet r0, r1;
    load_g(r0, 0);
    load_g(r1, 32);
    for (int k0 = 0; k0 < 1024; k0 += 64) {
        __syncthreads();
        store_l(r0);
        __syncthreads();
        if (k0 + 64 < 1024) load_g(r0, k0 + 64);
        mf();
        __syncthreads();
        store_l(r1);
        __syncthreads();
        if (k0 + 96 < 1024) load_g(r1, k0 + 96);
        mf();
    }

#pragma unroll
    for (int fm = 0; fm < 2; ++fm) {
        int rbase = row0 + wm * 32 + fm * 16 + (lane >> 4) * 4;
#pragma unroll
        for (int fn = 0; fn < 4; ++fn) {
            int c = col0 + wn * 64 + fn * 16 + (lane & 15);
#pragma unroll
            for (int q = 0; q < 4; ++q)
                gbuf[((size_t)(dir * NB + rbase + q)) * H4 + c] = acc[fm][fn][q];
        }
    }
}

// ---------------------------------------------------------------------------
__global__ __launch_bounds__(256)
void lstm_gate(int t, const int* __restrict__ lengths,
               const float* __restrict__ b_f, const float* __restrict__ b_b,
               const float* __restrict__ g_buf, float* __restrict__ ccur,
               unsigned short* __restrict__ hc_hi, unsigned short* __restrict__ hc_lo,
               unsigned short* __restrict__ h_hi, unsigned short* __restrict__ h_lo,
               float* __restrict__ c_seq)
{
    int b = blockIdx.x, dir = blockIdx.y, tid = threadIdx.x;
    const float* bias = dir ? b_b : b_f;
    int len = lengths[b];
    int pos = dir ? ((t < len) ? (len - 1 - t) : t) : t;
    const float* g = g_buf + ((size_t)(dir * NB + b)) * H4;
    float* cc = ccur + ((size_t)(dir * NB + b)) * HID;
    unsigned short* hch = hc_hi + ((size_t)(dir * NB + b)) * HID;
    unsigned short* hcl = hc_lo + ((size_t)(dir * NB + b)) * HID;
    size_t so = ((size_t)(b * LM + pos)) * D2 + dir * HID;
    for (int u = tid; u < HID; u += 256) {
        float gi = g[u]           + bias[u];
        float gf = g[HID + u]     + bias[HID + u];
        float gu = g[2 * HID + u] + bias[2 * HID + u];
        float go = g[3 * HID + u] + bias[3 * HID + u];
        float c = sigm(gf) * cc[u] + sigm(gi) * tanhf(gu);
        float h = sigm(go) * tanhf(c);
        cc[u] = c; c_seq[so + u] = c;
        unsigned short hb = bf16_rne(h);
        unsigned short hl2 = bf16_rne(h - bf16_tof(hb));
        hch[u] = hb; hcl[u] = hl2;
        h_hi[so + u] = hb; h_lo[so + u] = hl2;
    }
}

// ---------------------------------------------------------------------------
// Pair GEMM template, bf16x3 MFMA, 2-deep register-prefetch pipeline.
// ---------------------------------------------------------------------------
template<int BM, int BN, int NT, int KTOT>
__global__ __launch_bounds__(NT)
void gemm_pairs_t(const int4* __restrict__ rowlist, int nrows_lit,
                  const int* __restrict__ nrows_ptr, int cap,
                  const unsigned short* __restrict__ h_hi,
                  const unsigned short* __restrict__ h_lo,
                  const unsigned short* __restrict__ w_hi,
                  const unsigned short* __restrict__ w_lo,
                  float* __restrict__ vbuf)
{
    constexpr int NWN = NT / 128;      // waves along N (2 or 4)
    constexpr int WROWS = BM / 2;      // wave rows (32 or 64)
    constexpr int FM = WROWS / 16;     // 2 or 4

    int nrows = nrows_ptr ? *nrows_ptr : nrows_lit;
    const int row0 = blockIdx.x * BM;
    if (row0 >= nrows) return;
    const int col0 = blockIdx.y * BN;
    const int kbeg = blockIdx.z * KTOT;
    const int kend = kbeg + KTOT;
    float* vout = vbuf + (size_t)blockIdx.z * cap * D5;

    const int tid = threadIdx.x, lane = tid & 63, wid = tid >> 6;
    const int wm = wid / NWN, wn = wid % NWN;

    __shared__ __align__(16) unsigned short As[2][BM * ASTR];
    __shared__ __align__(16) unsigned short Bs[2][BN * BSTR];

    int s_arow, s_akp, s_apl, s_bcol, s_bx;
    if constexpr (NT == 256) {
        s_arow = tid & 63; s_akp = (tid >> 6) & 1; s_apl = tid >> 7;
        s_bcol = (tid & 63) + (((tid >> 6) & 1) << 6); s_bx = tid >> 7;  // b_kp
    } else {
        s_arow = tid & 127; s_apl = tid >> 8; s_akp = (tid >> 7) & 1;
        s_bcol = tid & 255; s_bx = tid >> 8;                             // b_plane
    }
    int rr = row0 + s_arow; if (rr > nrows - 1) rr = nrows - 1;
    int4 e = rowlist[rr];
    if (e.x < 0) { e.x = 0; e.y = 0; e.z = 1; }
    const unsigned short* aL = (s_apl ? h_lo : h_hi) + ((size_t)(e.x * LM + e.y)) * D2;
    const unsigned short* aR = (s_apl ? h_lo : h_hi) + ((size_t)(e.x * LM + e.z)) * D2;
    const unsigned short* whp = w_hi + ((size_t)(col0 + s_bcol)) * H4;
    const unsigned short* wlp = w_lo + ((size_t)(col0 + s_bcol)) * H4;

    auto load_g = [&](RegSet& r, int k0) {
        const unsigned short* asrc = (k0 < D2) ? (aL + k0) : (aR + (k0 - D2));
        r.a0 = *(const uint4*)(asrc + s_akp * 8);
        r.a1 = *(const uint4*)(asrc + s_akp * 8 + 16);
        if constexpr (NT == 256) {
            r.b0 = *(const uint4*)(whp + k0 + s_bx * 8);
            r.b1 = *(const uint4*)(whp + k0 + s_bx * 8 + 16);
            r.b2 = *(const uint4*)(wlp + k0 + s_bx * 8);
            r.b3 = *(const uint4*)(wlp + k0 + s_bx * 8 + 16);
        } else {
            const unsigned short* wp = s_bx ? wlp : whp;
            r.b0 = *(const uint4*)(wp + k0);
            r.b1 = *(const uint4*)(wp + k0 + 8);
            r.b2 = *(const uint4*)(wp + k0 + 16);
            r.b3 = *(const uint4*)(wp + k0 + 24);
        }
    };
    auto store_l = [&](const RegSet& r) {
        *(uint4*)&As[s_apl][s_arow * ASTR + s_akp * 8]      = r.a0;
        *(uint4*)&As[s_apl][s_arow * ASTR + s_akp * 8 + 16] = r.a1;
        if constexpr (NT == 256) {
            *(uint4*)&Bs[0][s_bcol * BSTR + s_bx * 8]      = r.b0;
            *(uint4*)&Bs[0][s_bcol * BSTR + s_bx * 8 + 16] = r.b1;
            *(uint4*)&Bs[1][s_bcol * BSTR + s_bx * 8]      = r.b2;
            *(uint4*)&Bs[1][s_bcol * BSTR + s_bx * 8 + 16] = r.b3;
        } else {
            *(uint4*)&Bs[s_bx][s_bcol * BSTR + 0]  = r.b0;
            *(uint4*)&Bs[s_bx][s_bcol * BSTR + 8]  = r.b1;
            *(uint4*)&Bs[s_bx][s_bcol * BSTR + 16] = r.b2;
            *(uint4*)&Bs[s_bx][s_bcol * BSTR + 24] = r.b3;
        }
    };

    f32x4 acc[FM][4];
#pragma unroll
    for (int i = 0; i < FM; ++i)
#pragma unroll
        for (int j = 0; j < 4; ++j) acc[i][j] = (f32x4){0.f, 0.f, 0.f, 0.f};

    const int a_off = (wm * WROWS + (lane & 15)) * ASTR + (lane >> 4) * 8;
    const int b_off = (wn * 64 + (lane & 15)) * BSTR + (lane >> 4) * 8;

    auto mf = [&]() {
        bf16x8 ah[FM], al[FM];
#pragma unroll
        for (int fm = 0; fm < FM; ++fm) {
            ah[fm] = *(const bf16x8*)&As[0][a_off + fm * 16 * ASTR];
            al[fm] = *(const bf16x8*)&As[1][a_off + fm * 16 * ASTR];
        }
#pragma unroll
        for (int fn = 0; fn < 4; ++fn) {
            bf16x8 bh = *(const bf16x8*)&Bs[0][b_off + fn * 16 * BSTR];
            bf16x8 bl = *(const bf16x8*)&Bs[1][b_off + fn * 16 * BSTR];
#pragma unroll
            for (int fm = 0; fm < FM; ++fm) {
                acc[fm][fn] = __builtin_amdgcn_mfma_f32_16x16x32_bf16(ah[fm], bh, acc[fm][fn], 0, 0, 0);
                acc[fm][fn] = __builtin_amdgcn_mfma_f32_16x16x32_bf16(ah[fm], bl, acc[fm][fn], 0, 0, 0);
                acc[fm][fn] = __builtin_amdgcn_mfma_f32_16x16x32_bf16(al[fm], bh, acc[fm][fn], 0, 0, 0);
            }
        }
    };

    RegSet r0, r1;
    load_g(r0, kbeg);
    load_g(r1, kbeg + 32);
    for (int k0 = kbeg; k0 < kend; k0 += 64) {
        __syncthreads();
        store_l(r0);
        __syncthreads();
        if (k0 + 64 < kend) load_g(r0, k0 + 64);
        mf();
        __syncthreads();
        store_l(r1);
        __syncthreads();
        if (k0 + 96 < kend) load_g(r1, k0 + 96);
        mf();
    }

#pragma unroll
    for (int fm = 0; fm < FM; ++fm) {
        int rbase = row0 + wm * WROWS + fm * 16 + (lane >> 4) * 4;
#pragma unroll
        for (int fn = 0; fn < 4; ++fn) {
            int c = col0 + wn * 64 + fn * 16 + (lane & 15);
#pragma unroll
            for (int q = 0; q < 4; ++q) {
                int r = rbase + q;
                if (r < nrows) vout[(size_t)r * D5 + c] = acc[fm][fn][q];
            }
        }
    }
}

// ---------------------------------------------------------------------------
__global__ __launch_bounds__(256)
void gates_logits(const int4* __restrict__ rowlist, int nrows_lit,
                  const int* __restrict__ nrows_ptr,
                  const float* __restrict__ v_buf, const float* __restrict__ v_buf2,
                  const float* __restrict__ b_comp,
                  const float* __restrict__ c_seq, const float* __restrict__ w_q,
                  float* __restrict__ nh_cand, float* __restrict__ nc_cand,
                  float* __restrict__ logits)
{
    int nrows = nrows_ptr ? *nrows_ptr : nrows_lit;
    int row = blockIdx.x;
    if (row >= nrows) return;
    int4 e = rowlist[row];
    if (e.x < 0) return;
    int b = e.x, sL = e.y, sR = e.z;
    int cslot = e.w & 0xffff, plog = e.w >> 16;
    const float* v = v_buf + (size_t)row * D5;
    const float* v2 = v_buf2 ? (v_buf2 + (size_t)row * D5) : nullptr;
    const float* cl = c_seq + ((size_t)(b * LM + sL)) * D2;
    const float* cr = c_seq + ((size_t)(b * LM + sR)) * D2;
    float* nh = nh_cand + ((size_t)(b * 15 + cslot)) * D2;
    float* nc = nc_cand + ((size_t)(b * 15 + cslot)) * D2;

    float part = 0.f;
    for (int d = threadIdx.x; d < D2; d += 256) {
        float gi  = v[d];
        float gfl = v[D2 + d];
        float gfr = v[2 * D2 + d];
        float gu  = v[3 * D2 + d];
        float go  = v[4 * D2 + d];
        if (v2) {
            gi += v2[d]; gfl += v2[D2 + d]; gfr += v2[2 * D2 + d];
            gu += v2[3 * D2 + d]; go += v2[4 * D2 + d];
        }
        gi += b_comp[d]; gfl += b_comp[D2 + d]; gfr += b_comp[2 * D2 + d];
        gu += b_comp[3 * D2 + d]; go += b_comp[4 * D2 + d];
        float c = cl[d] * sigm(gfl + 1.0f) + cr[d] * sigm(gfr + 1.0f) + tanhf(gu) * sigm(gi);
        float h = sigm(go) * tanhf(c);
        nc[d] = c; nh[d] = h;
        part += h * w_q[d];
    }
    for (int o = 32; o > 0; o >>= 1) part += __shfl_down(part, o);
    __shared__ float wsum[4];
    if ((threadIdx.x & 63) == 0) wsum[threadIdx.x >> 6] = part;
    __syncthreads();
    if (threadIdx.x == 0) logits[b * 16 + plog] = wsum[0] + wsum[1] + wsum[2] + wsum[3];
}

// ---------------------------------------------------------------------------
__global__ __launch_bounds__(256)
void merge_kernel(int iter, const int* __restrict__ lengths,
                  float* __restrict__ c_seq,
                  const float* __restrict__ nh_cand, const float* __restrict__ nc_cand,
                  float* __restrict__ logits, int* __restrict__ pos_idx,
                  int* __restrict__ pair_idx, int4* __restrict__ rowlist_out,
                  int* __restrict__ rcount,
                  unsigned short* __restrict__ h_hi, unsigned short* __restrict__ h_lo)
{
    int b = blockIdx.x, tid = threadIdx.x;
    int M = 15 - iter;
    int len = lengths[b];
    bool act = (iter + 1) < len;

    __shared__ float sl[16];
    __shared__ int sp[16], sq[16];
    __shared__ int s_sel;

    if (tid <= M) sp[tid] = pos_idx[b * 16 + tid];
    if (tid < M) { sq[tid] = pair_idx[b * 16 + tid]; sl[tid] = logits[b * 16 + tid]; }
    __syncthreads();

    if (tid == 0) {
        int sel = -1;
        if (act) {
            float best = -INFINITY; sel = 0;
            for (int p2 = 0; p2 < M; ++p2) {
                float mv = ((iter + 1 + p2) < len) ? sl[p2] : (sl[p2] - 10000.0f);
                if (mv > best) { best = mv; sel = p2; }
            }
        }
        s_sel = sel;
    }
    __syncthreads();
    int sel = s_sel;

    if (sel >= 0) {
        int slotL = sp[sel];
        int cslot = sq[sel];
        const float* nh = nh_cand + ((size_t)(b * 15 + cslot)) * D2;
        const float* nc = nc_cand + ((size_t)(b * 15 + cslot)) * D2;
        float* cd = c_seq + ((size_t)(b * LM + slotL)) * D2;
        unsigned short* hh = h_hi + ((size_t)(b * LM + slotL)) * D2;
        unsigned short* hl = h_lo + ((size_t)(b * LM + slotL)) * D2;
        for (int d = tid; d < D2; d += 256) {
            float hv = nh[d];
            cd[d] = nc[d];
            unsigned short hb = bf16_rne(hv);
            hh[d] = hb;
            hl[d] = bf16_rne(hv - bf16_tof(hb));
        }

        if (tid == 0) {
            for (int p2 = sel + 1; p2 < M; ++p2) sp[p2] = sp[p2 + 1];
            for (int p2 = sel + 1; p2 < M - 1; ++p2) { sq[p2] = sq[p2 + 1]; sl[p2] = sl[p2 + 1]; }
            int Mn = M - 1;
            if (iter < 14) {
                if (sel - 1 >= 0) {
                    int4 e0 = make_int4(b, sp[sel - 1], sp[sel], sq[sel - 1] | ((sel - 1) << 16));
                    int i0 = atomicAdd(rcount, 1);
                    rowlist_out[i0] = e0;
                }
                if (sel <= Mn - 1) {
                    int4 e1 = make_int4(b, sp[sel], sp[sel + 1], sq[sel] | (sel << 16));
                    int i1 = atomicAdd(rcount, 1);
                    rowlist_out[i1] = e1;
                }
            }
            for (int p2 = 0; p2 < M; ++p2) pos_idx[b * 16 + p2] = sp[p2];
            for (int p2 = 0; p2 < Mn; ++p2) { pair_idx[b * 16 + p2] = sq[p2]; logits[b * 16 + p2] = sl[p2]; }
        }
    }
}

__global__ __launch_bounds__(256)
void copy_out(const unsigned short* __restrict__ h_hi,
              const unsigned short* __restrict__ h_lo, float* __restrict__ out)
{
    int b = blockIdx.x;
    size_t base = (size_t)(b * LM) * D2;
    for (int d = threadIdx.x; d < D2; d += 256)
        out[(size_t)b * D2 + d] = bf16_tof(h_hi[base + d]) + bf16_tof(h_lo[base + d]);
}

// ---------------------------------------------------------------------------
extern "C" void kernel_launch(void* const* d_in, const int* in_sizes, int n_in,
                              void* d_out, int out_size, void* d_ws, size_t ws_size,
                              hipStream_t stream)
{
    const float* x      = (const float*)d_in[0];
    const int*   lens   = (const int*)  d_in[1];
    const float* w_ih_f = (const float*)d_in[2];
    const float* w_hh_f = (const float*)d_in[3];
    const float* b_f    = (const float*)d_in[4];
    const float* w_ih_b = (const float*)d_in[5];
    const float* w_hh_b = (const float*)d_in[6];
    const float* b_b    = (const float*)d_in[7];
    const float* w_comp = (const float*)d_in[8];
    const float* b_comp = (const float*)d_in[9];
    const float* w_q    = (const float*)d_in[10];
    float* out = (float*)d_out;

    char* p = (char*)d_ws;
    auto alloc = [&](size_t bytes) {
        char* q = p; p += (bytes + 255) & ~(size_t)255; return q;
    };
    float* c_seq = (float*)alloc((size_t)NB * LM * D2 * 4);
    float* nh    = (float*)alloc((size_t)NB * 15 * D2 * 4);
    float* nc    = (float*)alloc((size_t)NB * 15 * D2 * 4);
    unsigned short* h_hi = (unsigned short*)alloc((size_t)NB * LM * D2 * 2);
    unsigned short* h_lo = (unsigned short*)alloc((size_t)NB * LM * D2 * 2);
    unsigned short* w_hi = (unsigned short*)alloc((size_t)D5 * H4 * 2);
    unsigned short* w_lo = (unsigned short*)alloc((size_t)D5 * H4 * 2);
    unsigned short* x_hi = (unsigned short*)alloc((size_t)NB * LM * HID * 2);
    unsigned short* x_lo = (unsigned short*)alloc((size_t)NB * LM * HID * 2);
    unsigned short* wl_hi = (unsigned short*)alloc((size_t)2 * H4 * 1024 * 2);
    unsigned short* wl_lo = (unsigned short*)alloc((size_t)2 * H4 * 1024 * 2);
    unsigned short* hc_hi = (unsigned short*)alloc((size_t)2 * NB * HID * 2);
    unsigned short* hc_lo = (unsigned short*)alloc((size_t)2 * NB * HID * 2);
    float* ccur  = (float*)alloc((size_t)2 * NB * HID * 4);
    float* logits = (float*)alloc((size_t)NB * 16 * 4);
    int*   pos    = (int*)alloc((size_t)NB * 16 * 4);
    int*   pair   = (int*)alloc((size_t)NB * 16 * 4);
    int4*  rowlist0   = (int4*)alloc((size_t)NPAIR0 * 16);
    int4*  rowlist_inc= (int4*)alloc((size_t)INC_CAP * 16);
    int*   rcount = (int*)alloc(16 * 4);
    // tail: gbuf (LSTM, 4.2MB) then reused as vbuf (pairs)
    char* tail = p;
    float* gbuf = (float*)tail;
    float* vbuf = (float*)tail;

    size_t used = (size_t)(tail - (char*)d_ws);
    size_t avail = (ws_size > used) ? (ws_size - used) : 0;
    size_t maxc = avail / ((size_t)D5 * 4);
    if (maxc > (size_t)NPAIR0) maxc = NPAIR0;
    int chunk = ((int)maxc) & ~127;
    if (chunk < 1024) chunk = 1024;   // need >= 2*INC_CAP rows of vbuf anyway

    init_kernel<<<dim3(NB), dim3(256), 0, stream>>>(ccur, hc_hi, hc_lo, pos, pair, rowlist0, rcount);
    split_w<<<dim3(2048), dim3(256), 0, stream>>>((const float4*)w_comp, w_hi, w_lo, (int)((size_t)D5 * H4 / 4));
    split_w<<<dim3(1024), dim3(256), 0, stream>>>((const float4*)x, x_hi, x_lo, (int)((size_t)NB * LM * HID / 4));
    pack_lstm_w<<<dim3(1024), dim3(256), 0, stream>>>(w_ih_f, w_hh_f, w_ih_b, w_hh_b, wl_hi, wl_lo);

    // ---- bidirectional LSTM, 16 sequential steps (MFMA) ----
    for (int t = 0; t < 16; ++t) {
        gemm_lstm_mfma<<<dim3(16, 4, 2), dim3(256), 0, stream>>>(
            t, lens, x_hi, x_lo, hc_hi, hc_lo, wl_hi, wl_lo, gbuf);
        lstm_gate<<<dim3(NB, 2), dim3(256), 0, stream>>>(
            t, lens, b_f, b_b, gbuf, ccur, hc_hi, hc_lo, h_hi, h_lo, c_seq);
    }

    // ---- iter 0: candidates + logits for all 15 pairs/batch (chunked) ----
    for (int off = 0; off < NPAIR0; off += chunk) {
        int rows = NPAIR0 - off; if (rows > chunk) rows = chunk;
        int RT = (rows + 127) >> 7;
        gemm_pairs_t<128, 256, 512, 2048><<<dim3(RT, D5 / 256, 1), dim3(512), 0, stream>>>(
            rowlist0 + off, rows, (const int*)nullptr, 0,
            h_hi, h_lo, w_hi, w_lo, vbuf);
        gates_logits<<<dim3(rows), dim3(256), 0, stream>>>(
            rowlist0 + off, rows, (const int*)nullptr,
            vbuf, (const float*)nullptr, b_comp, c_seq, w_q, nh, nc, logits);
    }

    // ---- 14 selection iterations (compacted incremental, split-K x2) ----
    float* vbuf2 = vbuf + (size_t)INC_CAP * D5;
    for (int it = 0; it < 14; ++it) {
        merge_kernel<<<dim3(NB), dim3(256), 0, stream>>>(
            it, lens, c_seq, nh, nc, logits, pos, pair,
            rowlist_inc, rcount + it, h_hi, h_lo);
        gemm_pairs_t<64, 128, 256, 1024><<<dim3(8, D5 / 128, 2), dim3(256), 0, stream>>>(
            rowlist_inc, 0, (const int*)(rcount + it), INC_CAP,
            h_hi, h_lo, w_hi, w_lo, vbuf);
        gates_logits<<<dim3(INC_CAP), dim3(256), 0, stream>>>(
            rowlist_inc, 0, (const int*)(rcount + it),
            vbuf, vbuf2, b_comp, c_seq, w_q, nh, nc, logits);
    }
    merge_kernel<<<dim3(NB), dim3(256), 0, stream>>>(
        14, lens, c_seq, nh, nc, logits, pos, pair,
        rowlist_inc, rcount + 15, h_hi, h_lo);

    copy_out<<<dim3(NB), dim3(256), 0, stream>>>(h_hi, h_lo, out);
}

// Round 6
// 1980.320 us; speedup vs baseline: 2.9197x; 2.9197x over previous
//
#include <hip/hip_runtime.h>
#include <math.h>

#define NB 256
#define LM 16
#define HID 512
#define H4 2048
#define D2 1024
#define D5 5120
#define NPAIR0 3840   // 256*15
#define ASTR 40       // LSTM kernel LDS stride (shorts)
#define BSTR 40
#define INC_CAP 512   // max incremental rows (2 per batch)

typedef __attribute__((ext_vector_type(8))) short bf16x8;
typedef __attribute__((ext_vector_type(4))) float f32x4;

__device__ __forceinline__ float sigm(float x) { return 1.0f / (1.0f + expf(-x)); }

__device__ __forceinline__ unsigned short bf16_rne(float f) {
    union { float f; unsigned u; } v; v.f = f;
    unsigned u = v.u;
    return (unsigned short)((u + 0x7fffu + ((u >> 16) & 1u)) >> 16);
}
__device__ __forceinline__ float bf16_tof(unsigned short h) {
    union { unsigned u; float f; } v; v.u = ((unsigned)h) << 16;
    return v.f;
}

// async global->LDS, 16B per lane; dest = wave-uniform base + lane*16
__device__ __forceinline__ void gload16(const unsigned short* g, unsigned short* l) {
    __builtin_amdgcn_global_load_lds(
        (const __attribute__((address_space(1))) void*)(const void*)g,
        (__attribute__((address_space(3))) void*)(void*)l, 16, 0, 0);
}

// ---------------------------------------------------------------------------
__global__ __launch_bounds__(256)
void init_kernel(float* ccur, unsigned short* hc_hi, unsigned short* hc_lo,
                 int* pos, int* pair, int4* rowlist0, int* rcount)
{
    int b = blockIdx.x, tid = threadIdx.x;
    for (int u = tid; u < HID; u += 256) {
        ccur[(size_t)b * HID + u] = 0.f;
        ccur[((size_t)NB + b) * HID + u] = 0.f;
        hc_hi[(size_t)b * HID + u] = 0;
        hc_hi[((size_t)NB + b) * HID + u] = 0;
        hc_lo[(size_t)b * HID + u] = 0;
        hc_lo[((size_t)NB + b) * HID + u] = 0;
    }
    if (tid < 16) { pos[b * 16 + tid] = tid; pair[b * 16 + tid] = tid; }
    if (tid < 15) rowlist0[b * 15 + tid] = make_int4(b, tid, tid + 1, tid | (tid << 16));
    if (b == 0 && tid < 16) rcount[tid] = 0;
}

// ---------------------------------------------------------------------------
__global__ __launch_bounds__(256)
void split_w(const float4* __restrict__ w, unsigned short* __restrict__ hi,
             unsigned short* __restrict__ lo, int n4)
{
    for (int i = blockIdx.x * 256 + threadIdx.x; i < n4; i += gridDim.x * 256) {
        float4 f = w[i];
        ushort4 h, l;
        h.x = bf16_rne(f.x); l.x = bf16_rne(f.x - bf16_tof(h.x));
        h.y = bf16_rne(f.y); l.y = bf16_rne(f.y - bf16_tof(h.y));
        h.z = bf16_rne(f.z); l.z = bf16_rne(f.z - bf16_tof(h.z));
        h.w = bf16_rne(f.w); l.w = bf16_rne(f.w - bf16_tof(h.w));
        ((ushort4*)hi)[i] = h;
        ((ushort4*)lo)[i] = l;
    }
}

// ---------------------------------------------------------------------------
__global__ __launch_bounds__(256)
void pack_lstm_w(const float* __restrict__ w_ih_f, const float* __restrict__ w_hh_f,
                 const float* __restrict__ w_ih_b, const float* __restrict__ w_hh_b,
                 unsigned short* __restrict__ wl_hi, unsigned short* __restrict__ wl_lo)
{
    const int total4 = 2 * H4 * 256;
    for (int i = blockIdx.x * 256 + threadIdx.x; i < total4; i += gridDim.x * 256) {
        int k4 = i & 255;
        int j = (i >> 8) & 2047;
        int dir = i >> 19;
        const float* wih = dir ? w_ih_b : w_ih_f;
        const float* whh = dir ? w_hh_b : w_hh_f;
        float4 f = (k4 < 128) ? *(const float4*)(wih + (size_t)j * HID + k4 * 4)
                              : *(const float4*)(whh + (size_t)j * HID + (k4 - 128) * 4);
        ushort4 h, l;
        h.x = bf16_rne(f.x); l.x = bf16_rne(f.x - bf16_tof(h.x));
        h.y = bf16_rne(f.y); l.y = bf16_rne(f.y - bf16_tof(h.y));
        h.z = bf16_rne(f.z); l.z = bf16_rne(f.z - bf16_tof(h.z));
        h.w = bf16_rne(f.w); l.w = bf16_rne(f.w - bf16_tof(h.w));
        ((ushort4*)wl_hi)[i] = h;
        ((ushort4*)wl_lo)[i] = l;
    }
}

// ---------------------------------------------------------------------------
// LSTM step GEMM, bf16x3 MFMA (round-4 proven version, 1-deep reg prefetch).
// ---------------------------------------------------------------------------
__global__ __launch_bounds__(256)
void gemm_lstm_mfma(int t, const int* __restrict__ lens,
                    const unsigned short* __restrict__ x_hi, const unsigned short* __restrict__ x_lo,
                    const unsigned short* __restrict__ hc_hi, const unsigned short* __restrict__ hc_lo,
                    const unsigned short* __restrict__ wl_hi, const unsigned short* __restrict__ wl_lo,
                    float* __restrict__ gbuf)
{
    const int col0 = blockIdx.x * 128, row0 = blockIdx.y * 64, dir = blockIdx.z;
    const int tid = threadIdx.x, lane = tid & 63, wid = tid >> 6;
    const int wm = wid >> 1, wn = wid & 1;

    __shared__ __align__(16) unsigned short As[2][64 * ASTR];
    __shared__ __align__(16) unsigned short Bs[2][128 * BSTR];

    const int s_row = tid & 63, s_kp = (tid >> 6) & 1, s_pl = tid >> 7;
    const int b = row0 + s_row;
    const int len = lens[b];
    const int trow = dir ? ((t < len) ? (len - 1 - t) : t) : t;
    const unsigned short* xp = (s_pl ? x_lo : x_hi) + ((size_t)(b * LM + trow)) * HID;
    const unsigned short* hp = (s_pl ? hc_lo : hc_hi) + ((size_t)(dir * NB + b)) * HID;

    const int b_col = (tid & 63) + (((tid >> 6) & 1) << 6), b_kp = tid >> 7;
    const unsigned short* whp = wl_hi + ((size_t)(dir * H4 + col0 + b_col)) * 1024;
    const unsigned short* wlp = wl_lo + ((size_t)(dir * H4 + col0 + b_col)) * 1024;

    uint4 rA0, rA1, rB0, rB1, rB2, rB3;
    auto load_g = [&](int k0) {
        const unsigned short* asrc = (k0 < HID) ? (xp + k0) : (hp + (k0 - HID));
        rA0 = *(const uint4*)(asrc + s_kp * 8);
        rA1 = *(const uint4*)(asrc + s_kp * 8 + 16);
        rB0 = *(const uint4*)(whp + k0 + b_kp * 8);
        rB1 = *(const uint4*)(whp + k0 + b_kp * 8 + 16);
        rB2 = *(const uint4*)(wlp + k0 + b_kp * 8);
        rB3 = *(const uint4*)(wlp + k0 + b_kp * 8 + 16);
    };
    auto store_l = [&]() {
        *(uint4*)&As[s_pl][s_row * ASTR + s_kp * 8]      = rA0;
        *(uint4*)&As[s_pl][s_row * ASTR + s_kp * 8 + 16] = rA1;
        *(uint4*)&Bs[0][b_col * BSTR + b_kp * 8]      = rB0;
        *(uint4*)&Bs[0][b_col * BSTR + b_kp * 8 + 16] = rB1;
        *(uint4*)&Bs[1][b_col * BSTR + b_kp * 8]      = rB2;
        *(uint4*)&Bs[1][b_col * BSTR + b_kp * 8 + 16] = rB3;
    };

    f32x4 acc[2][4];
#pragma unroll
    for (int i = 0; i < 2; ++i)
#pragma unroll
        for (int j = 0; j < 4; ++j) acc[i][j] = (f32x4){0.f, 0.f, 0.f, 0.f};

    const int a_off = (wm * 32 + (lane & 15)) * ASTR + (lane >> 4) * 8;
    const int b_off = (wn * 64 + (lane & 15)) * BSTR + (lane >> 4) * 8;

    load_g(0);
    for (int k0 = 0; k0 < 1024; k0 += 32) {
        __syncthreads();
        store_l();
        __syncthreads();
        if (k0 + 32 < 1024) load_g(k0 + 32);
        bf16x8 ah[2], al[2];
#pragma unroll
        for (int fm = 0; fm < 2; ++fm) {
            ah[fm] = *(const bf16x8*)&As[0][a_off + fm * 16 * ASTR];
            al[fm] = *(const bf16x8*)&As[1][a_off + fm * 16 * ASTR];
        }
#pragma unroll
        for (int fn = 0; fn < 4; ++fn) {
            bf16x8 bh = *(const bf16x8*)&Bs[0][b_off + fn * 16 * BSTR];
            bf16x8 bl = *(const bf16x8*)&Bs[1][b_off + fn * 16 * BSTR];
#pragma unroll
            for (int fm = 0; fm < 2; ++fm) {
                acc[fm][fn] = __builtin_amdgcn_mfma_f32_16x16x32_bf16(ah[fm], bh, acc[fm][fn], 0, 0, 0);
                acc[fm][fn] = __builtin_amdgcn_mfma_f32_16x16x32_bf16(ah[fm], bl, acc[fm][fn], 0, 0, 0);
                acc[fm][fn] = __builtin_amdgcn_mfma_f32_16x16x32_bf16(al[fm], bh, acc[fm][fn], 0, 0, 0);
            }
        }
    }

#pragma unroll
    for (int fm = 0; fm < 2; ++fm) {
        int rbase = row0 + wm * 32 + fm * 16 + (lane >> 4) * 4;
#pragma unroll
        for (int fn = 0; fn < 4; ++fn) {
            int c = col0 + wn * 64 + fn * 16 + (lane & 15);
#pragma unroll
            for (int q = 0; q < 4; ++q)
                gbuf[((size_t)(dir * NB + rbase + q)) * H4 + c] = acc[fm][fn][q];
        }
    }
}

// ---------------------------------------------------------------------------
__global__ __launch_bounds__(256)
void lstm_gate(int t, const int* __restrict__ lengths,
               const float* __restrict__ b_f, const float* __restrict__ b_b,
               const float* __restrict__ g_buf, float* __restrict__ ccur,
               unsigned short* __restrict__ hc_hi, unsigned short* __restrict__ hc_lo,
               unsigned short* __restrict__ h_hi, unsigned short* __restrict__ h_lo,
               float* __restrict__ c_seq)
{
    int b = blockIdx.x, dir = blockIdx.y, tid = threadIdx.x;
    const float* bias = dir ? b_b : b_f;
    int len = lengths[b];
    int pos = dir ? ((t < len) ? (len - 1 - t) : t) : t;
    const float* g = g_buf + ((size_t)(dir * NB + b)) * H4;
    float* cc = ccur + ((size_t)(dir * NB + b)) * HID;
    unsigned short* hch = hc_hi + ((size_t)(dir * NB + b)) * HID;
    unsigned short* hcl = hc_lo + ((size_t)(dir * NB + b)) * HID;
    size_t so = ((size_t)(b * LM + pos)) * D2 + dir * HID;
    for (int u = tid; u < HID; u += 256) {
        float gi = g[u]           + bias[u];
        float gf = g[HID + u]     + bias[HID + u];
        float gu = g[2 * HID + u] + bias[2 * HID + u];
        float go = g[3 * HID + u] + bias[3 * HID + u];
        float c = sigm(gf) * cc[u] + sigm(gi) * tanhf(gu);
        float h = sigm(go) * tanhf(c);
        cc[u] = c; c_seq[so + u] = c;
        unsigned short hb = bf16_rne(h);
        unsigned short hl2 = bf16_rne(h - bf16_tof(hb));
        hch[u] = hb; hcl[u] = hl2;
        h_hi[so + u] = hb; h_lo[so + u] = hl2;
    }
}

// ---------------------------------------------------------------------------
// Pair GEMM: global_load_lds staging, double-buffered LDS, 1 barrier/K-step.
// Tile BM x 128, 4 waves (2x2). LDS rows are 32 shorts (64B), XOR-swizzled:
// store source part (lane&3)^((lane>>3)&3); read slot (lane>>4)^((lane>>1)&3).
// ---------------------------------------------------------------------------
template<int BM, int KTOT>
__global__ __launch_bounds__(256)
void gemm_pairs_g(const int4* __restrict__ rowlist, int nrows_lit,
                  const int* __restrict__ nrows_ptr, int cap,
                  const unsigned short* __restrict__ h_hi,
                  const unsigned short* __restrict__ h_lo,
                  const unsigned short* __restrict__ w_hi,
                  const unsigned short* __restrict__ w_lo,
                  float* __restrict__ vbuf)
{
    constexpr int WROWS = BM / 2;       // 32 or 64
    constexpr int FM = WROWS / 16;      // 2 or 4
    constexpr int NRS = BM / 64;        // row-sets per wave (1 or 2)
    constexpr int SA = BM * 32;         // shorts per A plane
    constexpr int SB = 128 * 32;        // shorts per B plane
    constexpr int BUF = 2 * SA + 2 * SB;

    int nrows = nrows_ptr ? *nrows_ptr : nrows_lit;
    const int row0 = blockIdx.x * BM;
    if (row0 >= nrows) return;
    const int col0 = blockIdx.y * 128;
    const int kbeg = blockIdx.z * KTOT;
    const int kend = kbeg + KTOT;
    float* vout = vbuf + (size_t)blockIdx.z * cap * D5;

    const int tid = threadIdx.x, lane = tid & 63, w = tid >> 6;
    const int wm = w >> 1, wn = w & 1;

    __shared__ __align__(16) unsigned short smem[2 * BUF];

    // ---- per-lane staging sources ----
    const int sz8 = ((lane & 3) ^ ((lane >> 3) & 3)) * 8;  // swizzled source part
    size_t offL[NRS], offR[NRS];
#pragma unroll
    for (int rs = 0; rs < NRS; ++rs) {
        int rr = row0 + (w + 4 * rs) * 16 + (lane >> 2);
        if (rr > nrows - 1) rr = nrows - 1;
        int4 e = rowlist[rr];
        if (e.x < 0) { e.x = 0; e.y = 0; e.z = 1; }
        offL[rs] = ((size_t)(e.x * LM + e.y)) * D2;
        offR[rs] = ((size_t)(e.x * LM + e.z)) * D2;
    }
    size_t colOff[2];
#pragma unroll
    for (int cs = 0; cs < 2; ++cs)
        colOff[cs] = ((size_t)(col0 + (w + 4 * cs) * 16 + (lane >> 2))) * H4;

    auto stage = [&](int d, int k) {
        unsigned short* sb = smem + d * BUF;
        // A: 2*NRS chunks per wave
#pragma unroll
        for (int j = 0; j < 2 * NRS; ++j) {
            const int pl = j / NRS, rs = j % NRS;
            const int g = w + 4 * rs;
            const unsigned short* hb = pl ? h_lo : h_hi;
            size_t off = (k < D2) ? (offL[rs] + k) : (offR[rs] + (k - D2));
            gload16(hb + off + sz8, sb + pl * SA + g * 512);
        }
        // B: 4 chunks per wave
#pragma unroll
        for (int j = 0; j < 4; ++j) {
            const int pl = j >> 1, cs = j & 1;
            const int g = w + 4 * cs;
            const unsigned short* wb = pl ? w_lo : w_hi;
            gload16(wb + colOff[cs] + k + sz8, sb + 2 * SA + pl * SB + g * 512);
        }
    };

    f32x4 acc[FM][4];
#pragma unroll
    for (int i = 0; i < FM; ++i)
#pragma unroll
        for (int j = 0; j < 4; ++j) acc[i][j] = (f32x4){0.f, 0.f, 0.f, 0.f};

    const int rsw = ((lane >> 4) ^ ((lane >> 1) & 3)) * 8;   // swizzled read slot
    const int a_off = (wm * WROWS + (lane & 15)) * 32 + rsw;
    const int b_off = 2 * SA + (wn * 64 + (lane & 15)) * 32 + rsw;

    stage(0, kbeg);
    __syncthreads();
    int cur = 0;
    for (int k0 = kbeg; k0 < kend; k0 += 32) {
        if (k0 + 32 < kend) stage(cur ^ 1, k0 + 32);
        const unsigned short* sb = smem + cur * BUF;
        bf16x8 ah[FM], al[FM];
#pragma unroll
        for (int fm = 0; fm < FM; ++fm) {
            ah[fm] = *(const bf16x8*)&sb[a_off + fm * 512];
            al[fm] = *(const bf16x8*)&sb[SA + a_off + fm * 512];
        }
#pragma unroll
        for (int fn = 0; fn < 4; ++fn) {
            bf16x8 bh = *(const bf16x8*)&sb[b_off + fn * 512];
            bf16x8 bl = *(const bf16x8*)&sb[SB + b_off + fn * 512];
#pragma unroll
            for (int fm = 0; fm < FM; ++fm) {
                acc[fm][fn] = __builtin_amdgcn_mfma_f32_16x16x32_bf16(ah[fm], bh, acc[fm][fn], 0, 0, 0);
                acc[fm][fn] = __builtin_amdgcn_mfma_f32_16x16x32_bf16(ah[fm], bl, acc[fm][fn], 0, 0, 0);
                acc[fm][fn] = __builtin_amdgcn_mfma_f32_16x16x32_bf16(al[fm], bh, acc[fm][fn], 0, 0, 0);
            }
        }
        __syncthreads();
        cur ^= 1;
    }

#pragma unroll
    for (int fm = 0; fm < FM; ++fm) {
        int rbase = row0 + wm * WROWS + fm * 16 + (lane >> 4) * 4;
#pragma unroll
        for (int fn = 0; fn < 4; ++fn) {
            int c = col0 + wn * 64 + fn * 16 + (lane & 15);
#pragma unroll
            for (int q = 0; q < 4; ++q) {
                int r = rbase + q;
                if (r < nrows) vout[(size_t)r * D5 + c] = acc[fm][fn][q];
            }
        }
    }
}

// ---------------------------------------------------------------------------
__global__ __launch_bounds__(256)
void gates_logits(const int4* __restrict__ rowlist, int nrows_lit,
                  const int* __restrict__ nrows_ptr,
                  const float* __restrict__ v_buf, const float* __restrict__ v_buf2,
                  const float* __restrict__ b_comp,
                  const float* __restrict__ c_seq, const float* __restrict__ w_q,
                  float* __restrict__ nh_cand, float* __restrict__ nc_cand,
                  float* __restrict__ logits)
{
    int nrows = nrows_ptr ? *nrows_ptr : nrows_lit;
    int row = blockIdx.x;
    if (row >= nrows) return;
    int4 e = rowlist[row];
    if (e.x < 0) return;
    int b = e.x, sL = e.y, sR = e.z;
    int cslot = e.w & 0xffff, plog = e.w >> 16;
    const float* v = v_buf + (size_t)row * D5;
    const float* v2 = v_buf2 ? (v_buf2 + (size_t)row * D5) : nullptr;
    const float* cl = c_seq + ((size_t)(b * LM + sL)) * D2;
    const float* cr = c_seq + ((size_t)(b * LM + sR)) * D2;
    float* nh = nh_cand + ((size_t)(b * 15 + cslot)) * D2;
    float* nc = nc_cand + ((size_t)(b * 15 + cslot)) * D2;

    float part = 0.f;
    for (int d = threadIdx.x; d < D2; d += 256) {
        float gi  = v[d];
        float gfl = v[D2 + d];
        float gfr = v[2 * D2 + d];
        float gu  = v[3 * D2 + d];
        float go  = v[4 * D2 + d];
        if (v2) {
            gi += v2[d]; gfl += v2[D2 + d]; gfr += v2[2 * D2 + d];
            gu += v2[3 * D2 + d]; go += v2[4 * D2 + d];
        }
        gi += b_comp[d]; gfl += b_comp[D2 + d]; gfr += b_comp[2 * D2 + d];
        gu += b_comp[3 * D2 + d]; go += b_comp[4 * D2 + d];
        float c = cl[d] * sigm(gfl + 1.0f) + cr[d] * sigm(gfr + 1.0f) + tanhf(gu) * sigm(gi);
        float h = sigm(go) * tanhf(c);
        nc[d] = c; nh[d] = h;
        part += h * w_q[d];
    }
    for (int o = 32; o > 0; o >>= 1) part += __shfl_down(part, o);
    __shared__ float wsum[4];
    if ((threadIdx.x & 63) == 0) wsum[threadIdx.x >> 6] = part;
    __syncthreads();
    if (threadIdx.x == 0) logits[b * 16 + plog] = wsum[0] + wsum[1] + wsum[2] + wsum[3];
}

// ---------------------------------------------------------------------------
__global__ __launch_bounds__(256)
void merge_kernel(int iter, const int* __restrict__ lengths,
                  float* __restrict__ c_seq,
                  const float* __restrict__ nh_cand, const float* __restrict__ nc_cand,
                  float* __restrict__ logits, int* __restrict__ pos_idx,
                  int* __restrict__ pair_idx, int4* __restrict__ rowlist_out,
                  int* __restrict__ rcount,
                  unsigned short* __restrict__ h_hi, unsigned short* __restrict__ h_lo)
{
    int b = blockIdx.x, tid = threadIdx.x;
    int M = 15 - iter;
    int len = lengths[b];
    bool act = (iter + 1) < len;

    __shared__ float sl[16];
    __shared__ int sp[16], sq[16];
    __shared__ int s_sel;

    if (tid <= M) sp[tid] = pos_idx[b * 16 + tid];
    if (tid < M) { sq[tid] = pair_idx[b * 16 + tid]; sl[tid] = logits[b * 16 + tid]; }
    __syncthreads();

    if (tid == 0) {
        int sel = -1;
        if (act) {
            float best = -INFINITY; sel = 0;
            for (int p2 = 0; p2 < M; ++p2) {
                float mv = ((iter + 1 + p2) < len) ? sl[p2] : (sl[p2] - 10000.0f);
                if (mv > best) { best = mv; sel = p2; }
            }
        }
        s_sel = sel;
    }
    __syncthreads();
    int sel = s_sel;

    if (sel >= 0) {
        int slotL = sp[sel];
        int cslot = sq[sel];
        const float* nh = nh_cand + ((size_t)(b * 15 + cslot)) * D2;
        const float* nc = nc_cand + ((size_t)(b * 15 + cslot)) * D2;
        float* cd = c_seq + ((size_t)(b * LM + slotL)) * D2;
        unsigned short* hh = h_hi + ((size_t)(b * LM + slotL)) * D2;
        unsigned short* hl = h_lo + ((size_t)(b * LM + slotL)) * D2;
        for (int d = tid; d < D2; d += 256) {
            float hv = nh[d];
            cd[d] = nc[d];
            unsigned short hb = bf16_rne(hv);
            hh[d] = hb;
            hl[d] = bf16_rne(hv - bf16_tof(hb));
        }

        if (tid == 0) {
            for (int p2 = sel + 1; p2 < M; ++p2) sp[p2] = sp[p2 + 1];
            for (int p2 = sel + 1; p2 < M - 1; ++p2) { sq[p2] = sq[p2 + 1]; sl[p2] = sl[p2 + 1]; }
            int Mn = M - 1;
            if (iter < 14) {
                if (sel - 1 >= 0) {
                    int4 e0 = make_int4(b, sp[sel - 1], sp[sel], sq[sel - 1] | ((sel - 1) << 16));
                    int i0 = atomicAdd(rcount, 1);
                    rowlist_out[i0] = e0;
                }
                if (sel <= Mn - 1) {
                    int4 e1 = make_int4(b, sp[sel], sp[sel + 1], sq[sel] | (sel << 16));
                    int i1 = atomicAdd(rcount, 1);
                    rowlist_out[i1] = e1;
                }
            }
            for (int p2 = 0; p2 < M; ++p2) pos_idx[b * 16 + p2] = sp[p2];
            for (int p2 = 0; p2 < Mn; ++p2) { pair_idx[b * 16 + p2] = sq[p2]; logits[b * 16 + p2] = sl[p2]; }
        }
    }
}

__global__ __launch_bounds__(256)
void copy_out(const unsigned short* __restrict__ h_hi,
              const unsigned short* __restrict__ h_lo, float* __restrict__ out)
{
    int b = blockIdx.x;
    size_t base = (size_t)(b * LM) * D2;
    for (int d = threadIdx.x; d < D2; d += 256)
        out[(size_t)b * D2 + d] = bf16_tof(h_hi[base + d]) + bf16_tof(h_lo[base + d]);
}

// ---------------------------------------------------------------------------
extern "C" void kernel_launch(void* const* d_in, const int* in_sizes, int n_in,
                              void* d_out, int out_size, void* d_ws, size_t ws_size,
                              hipStream_t stream)
{
    const float* x      = (const float*)d_in[0];
    const int*   lens   = (const int*)  d_in[1];
    const float* w_ih_f = (const float*)d_in[2];
    const float* w_hh_f = (const float*)d_in[3];
    const float* b_f    = (const float*)d_in[4];
    const float* w_ih_b = (const float*)d_in[5];
    const float* w_hh_b = (const float*)d_in[6];
    const float* b_b    = (const float*)d_in[7];
    const float* w_comp = (const float*)d_in[8];
    const float* b_comp = (const float*)d_in[9];
    const float* w_q    = (const float*)d_in[10];
    float* out = (float*)d_out;

    char* p = (char*)d_ws;
    auto alloc = [&](size_t bytes) {
        char* q = p; p += (bytes + 255) & ~(size_t)255; return q;
    };
    float* c_seq = (float*)alloc((size_t)NB * LM * D2 * 4);
    float* nh    = (float*)alloc((size_t)NB * 15 * D2 * 4);
    float* nc    = (float*)alloc((size_t)NB * 15 * D2 * 4);
    unsigned short* h_hi = (unsigned short*)alloc((size_t)NB * LM * D2 * 2);
    unsigned short* h_lo = (unsigned short*)alloc((size_t)NB * LM * D2 * 2);
    unsigned short* w_hi = (unsigned short*)alloc((size_t)D5 * H4 * 2);
    unsigned short* w_lo = (unsigned short*)alloc((size_t)D5 * H4 * 2);
    unsigned short* x_hi = (unsigned short*)alloc((size_t)NB * LM * HID * 2);
    unsigned short* x_lo = (unsigned short*)alloc((size_t)NB * LM * HID * 2);
    unsigned short* wl_hi = (unsigned short*)alloc((size_t)2 * H4 * 1024 * 2);
    unsigned short* wl_lo = (unsigned short*)alloc((size_t)2 * H4 * 1024 * 2);
    unsigned short* hc_hi = (unsigned short*)alloc((size_t)2 * NB * HID * 2);
    unsigned short* hc_lo = (unsigned short*)alloc((size_t)2 * NB * HID * 2);
    float* ccur  = (float*)alloc((size_t)2 * NB * HID * 4);
    float* logits = (float*)alloc((size_t)NB * 16 * 4);
    int*   pos    = (int*)alloc((size_t)NB * 16 * 4);
    int*   pair   = (int*)alloc((size_t)NB * 16 * 4);
    int4*  rowlist0   = (int4*)alloc((size_t)NPAIR0 * 16);
    int4*  rowlist_inc= (int4*)alloc((size_t)INC_CAP * 16);
    int*   rcount = (int*)alloc(16 * 4);
    // tail: gbuf (LSTM, 4.2MB) then reused as vbuf (pairs)
    char* tail = p;
    float* gbuf = (float*)tail;
    float* vbuf = (float*)tail;

    size_t used = (size_t)(tail - (char*)d_ws);
    size_t avail = (ws_size > used) ? (ws_size - used) : 0;
    size_t maxc = avail / ((size_t)D5 * 4);
    if (maxc > (size_t)NPAIR0) maxc = NPAIR0;
    int chunk = ((int)maxc) & ~127;
    if (chunk < 1024) chunk = 1024;   // need >= 2*INC_CAP rows of vbuf anyway

    init_kernel<<<dim3(NB), dim3(256), 0, stream>>>(ccur, hc_hi, hc_lo, pos, pair, rowlist0, rcount);
    split_w<<<dim3(2048), dim3(256), 0, stream>>>((const float4*)w_comp, w_hi, w_lo, (int)((size_t)D5 * H4 / 4));
    split_w<<<dim3(1024), dim3(256), 0, stream>>>((const float4*)x, x_hi, x_lo, (int)((size_t)NB * LM * HID / 4));
    pack_lstm_w<<<dim3(1024), dim3(256), 0, stream>>>(w_ih_f, w_hh_f, w_ih_b, w_hh_b, wl_hi, wl_lo);

    // ---- bidirectional LSTM, 16 sequential steps (MFMA) ----
    for (int t = 0; t < 16; ++t) {
        gemm_lstm_mfma<<<dim3(16, 4, 2), dim3(256), 0, stream>>>(
            t, lens, x_hi, x_lo, hc_hi, hc_lo, wl_hi, wl_lo, gbuf);
        lstm_gate<<<dim3(NB, 2), dim3(256), 0, stream>>>(
            t, lens, b_f, b_b, gbuf, ccur, hc_hi, hc_lo, h_hi, h_lo, c_seq);
    }

    // ---- iter 0: candidates + logits for all 15 pairs/batch (chunked) ----
    for (int off = 0; off < NPAIR0; off += chunk) {
        int rows = NPAIR0 - off; if (rows > chunk) rows = chunk;
        int RT = (rows + 127) >> 7;
        gemm_pairs_g<128, 2048><<<dim3(RT, 40, 1), dim3(256), 0, stream>>>(
            rowlist0 + off, rows, (const int*)nullptr, 0,
            h_hi, h_lo, w_hi, w_lo, vbuf);
        gates_logits<<<dim3(rows), dim3(256), 0, stream>>>(
            rowlist0 + off, rows, (const int*)nullptr,
            vbuf, (const float*)nullptr, b_comp, c_seq, w_q, nh, nc, logits);
    }

    // ---- 14 selection iterations (compacted incremental, split-K x2) ----
    float* vbuf2 = vbuf + (size_t)INC_CAP * D5;
    for (int it = 0; it < 14; ++it) {
        merge_kernel<<<dim3(NB), dim3(256), 0, stream>>>(
            it, lens, c_seq, nh, nc, logits, pos, pair,
            rowlist_inc, rcount + it, h_hi, h_lo);
        gemm_pairs_g<64, 1024><<<dim3(8, 40, 2), dim3(256), 0, stream>>>(
            rowlist_inc, 0, (const int*)(rcount + it), INC_CAP,
            h_hi, h_lo, w_hi, w_lo, vbuf);
        gates_logits<<<dim3(INC_CAP), dim3(256), 0, stream>>>(
            rowlist_inc, 0, (const int*)(rcount + it),
            vbuf, vbuf2, b_comp, c_seq, w_q, nh, nc, logits);
    }
    merge_kernel<<<dim3(NB), dim3(256), 0, stream>>>(
        14, lens, c_seq, nh, nc, logits, pos, pair,
        rowlist_inc, rcount + 15, h_hi, h_lo);

    copy_out<<<dim3(NB), dim3(256), 0, stream>>>(h_hi, h_lo, out);
}

// Round 7
// 1496.593 us; speedup vs baseline: 3.8634x; 1.3232x over previous
//
#include <hip/hip_runtime.h>
#include <math.h>

#define NB 256
#define LM 16
#define HID 512
#define H4 2048
#define D2 1024
#define D5 5120
#define NPAIR0 3840   // 256*15
#define INC_CAP 512   // max incremental rows (2 per batch)

typedef __attribute__((ext_vector_type(8))) short bf16x8;
typedef __attribute__((ext_vector_type(4))) float f32x4;

__device__ __forceinline__ float sigm(float x) { return 1.0f / (1.0f + expf(-x)); }

__device__ __forceinline__ unsigned short bf16_rne(float f) {
    union { float f; unsigned u; } v; v.f = f;
    unsigned u = v.u;
    return (unsigned short)((u + 0x7fffu + ((u >> 16) & 1u)) >> 16);
}
__device__ __forceinline__ float bf16_tof(unsigned short h) {
    union { unsigned u; float f; } v; v.u = ((unsigned)h) << 16;
    return v.f;
}

// async global->LDS, 16B per lane; dest = wave-uniform base + lane*16
__device__ __forceinline__ void gload16(const unsigned short* g, unsigned short* l) {
    __builtin_amdgcn_global_load_lds(
        (const __attribute__((address_space(1))) void*)(const void*)g,
        (__attribute__((address_space(3))) void*)(void*)l, 16, 0, 0);
}

// ---------------------------------------------------------------------------
// init: zero LSTM state, slot maps, uncompacted + length-compacted rowlists,
// logits = -1e30 (missing pairs stay masked). rcount must be pre-zeroed.
// ---------------------------------------------------------------------------
__global__ __launch_bounds__(256)
void init_kernel(const int* __restrict__ lens, float* ccur,
                 unsigned short* hc_hi, unsigned short* hc_lo,
                 int* pos, int* pair, int4* rowlist0, int4* rowlist_c,
                 int* rcount, float* logits)
{
    int b = blockIdx.x, tid = threadIdx.x;
    for (int u = tid; u < HID; u += 256) {
        ccur[(size_t)b * HID + u] = 0.f;
        ccur[((size_t)NB + b) * HID + u] = 0.f;
        hc_hi[(size_t)b * HID + u] = 0;
        hc_hi[((size_t)NB + b) * HID + u] = 0;
        hc_lo[(size_t)b * HID + u] = 0;
        hc_lo[((size_t)NB + b) * HID + u] = 0;
    }
    if (tid < 16) { pos[b * 16 + tid] = tid; pair[b * 16 + tid] = tid; logits[b * 16 + tid] = -1e30f; }
    if (tid < 15) rowlist0[b * 15 + tid] = make_int4(b, tid, tid + 1, tid | (tid << 16));
    __shared__ int sbase;
    int len = lens[b];
    if (tid == 0) sbase = atomicAdd(rcount + 14, len - 1);
    __syncthreads();
    if (tid < len - 1) rowlist_c[sbase + tid] = make_int4(b, tid, tid + 1, tid | (tid << 16));
}

// ---------------------------------------------------------------------------
__global__ __launch_bounds__(256)
void split_w(const float4* __restrict__ w, unsigned short* __restrict__ hi,
             unsigned short* __restrict__ lo, int n4)
{
    for (int i = blockIdx.x * 256 + threadIdx.x; i < n4; i += gridDim.x * 256) {
        float4 f = w[i];
        ushort4 h, l;
        h.x = bf16_rne(f.x); l.x = bf16_rne(f.x - bf16_tof(h.x));
        h.y = bf16_rne(f.y); l.y = bf16_rne(f.y - bf16_tof(h.y));
        h.z = bf16_rne(f.z); l.z = bf16_rne(f.z - bf16_tof(h.z));
        h.w = bf16_rne(f.w); l.w = bf16_rne(f.w - bf16_tof(h.w));
        ((ushort4*)hi)[i] = h;
        ((ushort4*)lo)[i] = l;
    }
}

// ---------------------------------------------------------------------------
__global__ __launch_bounds__(256)
void pack_lstm_w(const float* __restrict__ w_ih_f, const float* __restrict__ w_hh_f,
                 const float* __restrict__ w_ih_b, const float* __restrict__ w_hh_b,
                 unsigned short* __restrict__ wl_hi, unsigned short* __restrict__ wl_lo)
{
    const int total4 = 2 * H4 * 256;
    for (int i = blockIdx.x * 256 + threadIdx.x; i < total4; i += gridDim.x * 256) {
        int k4 = i & 255;
        int j = (i >> 8) & 2047;
        int dir = i >> 19;
        const float* wih = dir ? w_ih_b : w_ih_f;
        const float* whh = dir ? w_hh_b : w_hh_f;
        float4 f = (k4 < 128) ? *(const float4*)(wih + (size_t)j * HID + k4 * 4)
                              : *(const float4*)(whh + (size_t)j * HID + (k4 - 128) * 4);
        ushort4 h, l;
        h.x = bf16_rne(f.x); l.x = bf16_rne(f.x - bf16_tof(h.x));
        h.y = bf16_rne(f.y); l.y = bf16_rne(f.y - bf16_tof(h.y));
        h.z = bf16_rne(f.z); l.z = bf16_rne(f.z - bf16_tof(h.z));
        h.w = bf16_rne(f.w); l.w = bf16_rne(f.w - bf16_tof(h.w));
        ((ushort4*)wl_hi)[i] = h;
        ((ushort4*)wl_lo)[i] = l;
    }
}

// ---------------------------------------------------------------------------
// LSTM step GEMM: gload_lds staging, double-buffered LDS, swizzled (same
// scheme as gemm_pairs_g). BM=64 batch rows x BN=128 cols, K=1024, FM=2.
// ---------------------------------------------------------------------------
__global__ __launch_bounds__(256)
void gemm_lstm_g(int t, const int* __restrict__ lens,
                 const unsigned short* __restrict__ x_hi, const unsigned short* __restrict__ x_lo,
                 const unsigned short* __restrict__ hc_hi, const unsigned short* __restrict__ hc_lo,
                 const unsigned short* __restrict__ wl_hi, const unsigned short* __restrict__ wl_lo,
                 float* __restrict__ gbuf)
{
    constexpr int SA = 64 * 32;        // shorts per A plane
    constexpr int SB = 128 * 32;       // shorts per B plane
    constexpr int BUF = 2 * SA + 2 * SB;

    const int row0 = blockIdx.x * 64;
    const int col0 = blockIdx.y * 128;
    const int dir = blockIdx.z;
    const int tid = threadIdx.x, lane = tid & 63, w = tid >> 6;
    const int wm = w >> 1, wn = w & 1;

    __shared__ __align__(16) unsigned short smem[2 * BUF];

    const int sz8 = ((lane & 3) ^ ((lane >> 3) & 3)) * 8;  // swizzled source part
    const int b0 = row0 + w * 16 + (lane >> 2);
    const int len = lens[b0];
    const int trow = dir ? ((t < len) ? (len - 1 - t) : t) : t;
    const size_t xoff = ((size_t)(b0 * LM + trow)) * HID;
    const size_t hoff = ((size_t)(dir * NB + b0)) * HID;

    size_t colOff[2];
#pragma unroll
    for (int cs = 0; cs < 2; ++cs)
        colOff[cs] = ((size_t)(dir * H4 + col0 + (w + 4 * cs) * 16 + (lane >> 2))) * 1024;

    auto stage = [&](int d, int k) {
        unsigned short* sb = smem + d * BUF;
        const unsigned short* sh = (k < HID) ? (x_hi + xoff + k) : (hc_hi + hoff + (k - HID));
        gload16(sh + sz8, sb + w * 512);
        const unsigned short* sl = (k < HID) ? (x_lo + xoff + k) : (hc_lo + hoff + (k - HID));
        gload16(sl + sz8, sb + SA + w * 512);
#pragma unroll
        for (int j = 0; j < 4; ++j) {
            const int pl = j >> 1, cs = j & 1;
            const unsigned short* wb = pl ? wl_lo : wl_hi;
            gload16(wb + colOff[cs] + k + sz8, sb + 2 * SA + pl * SB + (w + 4 * cs) * 512);
        }
    };

    f32x4 acc[2][4];
#pragma unroll
    for (int i = 0; i < 2; ++i)
#pragma unroll
        for (int j = 0; j < 4; ++j) acc[i][j] = (f32x4){0.f, 0.f, 0.f, 0.f};

    const int rsw = ((lane >> 4) ^ ((lane >> 1) & 3)) * 8;   // swizzled read slot
    const int a_off = (wm * 32 + (lane & 15)) * 32 + rsw;
    const int b_off = 2 * SA + (wn * 64 + (lane & 15)) * 32 + rsw;

    stage(0, 0);
    __syncthreads();
    int cur = 0;
    for (int k0 = 0; k0 < 1024; k0 += 32) {
        if (k0 + 32 < 1024) stage(cur ^ 1, k0 + 32);
        const unsigned short* sb = smem + cur * BUF;
        bf16x8 ah[2], al[2];
#pragma unroll
        for (int fm = 0; fm < 2; ++fm) {
            ah[fm] = *(const bf16x8*)&sb[a_off + fm * 512];
            al[fm] = *(const bf16x8*)&sb[SA + a_off + fm * 512];
        }
#pragma unroll
        for (int fn = 0; fn < 4; ++fn) {
            bf16x8 bh = *(const bf16x8*)&sb[b_off + fn * 512];
            bf16x8 bl = *(const bf16x8*)&sb[SB + b_off + fn * 512];
#pragma unroll
            for (int fm = 0; fm < 2; ++fm) {
                acc[fm][fn] = __builtin_amdgcn_mfma_f32_16x16x32_bf16(ah[fm], bh, acc[fm][fn], 0, 0, 0);
                acc[fm][fn] = __builtin_amdgcn_mfma_f32_16x16x32_bf16(ah[fm], bl, acc[fm][fn], 0, 0, 0);
                acc[fm][fn] = __builtin_amdgcn_mfma_f32_16x16x32_bf16(al[fm], bh, acc[fm][fn], 0, 0, 0);
            }
        }
        __syncthreads();
        cur ^= 1;
    }

#pragma unroll
    for (int fm = 0; fm < 2; ++fm) {
        int rbase = row0 + wm * 32 + fm * 16 + (lane >> 4) * 4;
#pragma unroll
        for (int fn = 0; fn < 4; ++fn) {
            int c = col0 + wn * 64 + fn * 16 + (lane & 15);
#pragma unroll
            for (int q = 0; q < 4; ++q)
                gbuf[((size_t)(dir * NB + rbase + q)) * H4 + c] = acc[fm][fn][q];
        }
    }
}

// ---------------------------------------------------------------------------
__global__ __launch_bounds__(256)
void lstm_gate(int t, const int* __restrict__ lengths,
               const float* __restrict__ b_f, const float* __restrict__ b_b,
               const float* __restrict__ g_buf, float* __restrict__ ccur,
               unsigned short* __restrict__ hc_hi, unsigned short* __restrict__ hc_lo,
               unsigned short* __restrict__ h_hi, unsigned short* __restrict__ h_lo,
               float* __restrict__ c_seq)
{
    int b = blockIdx.x, dir = blockIdx.y, tid = threadIdx.x;
    const float* bias = dir ? b_b : b_f;
    int len = lengths[b];
    int pos = dir ? ((t < len) ? (len - 1 - t) : t) : t;
    const float* g = g_buf + ((size_t)(dir * NB + b)) * H4;
    float* cc = ccur + ((size_t)(dir * NB + b)) * HID;
    unsigned short* hch = hc_hi + ((size_t)(dir * NB + b)) * HID;
    unsigned short* hcl = hc_lo + ((size_t)(dir * NB + b)) * HID;
    size_t so = ((size_t)(b * LM + pos)) * D2 + dir * HID;
    for (int u = tid; u < HID; u += 256) {
        float gi = g[u]           + bias[u];
        float gf = g[HID + u]     + bias[HID + u];
        float gu = g[2 * HID + u] + bias[2 * HID + u];
        float go = g[3 * HID + u] + bias[3 * HID + u];
        float c = sigm(gf) * cc[u] + sigm(gi) * tanhf(gu);
        float h = sigm(go) * tanhf(c);
        cc[u] = c; c_seq[so + u] = c;
        unsigned short hb = bf16_rne(h);
        unsigned short hl2 = bf16_rne(h - bf16_tof(hb));
        hch[u] = hb; hcl[u] = hl2;
        h_hi[so + u] = hb; h_lo[so + u] = hl2;
    }
}

// ---------------------------------------------------------------------------
// Pair GEMM: gload_lds staging, double-buffered LDS, 1 barrier/K-step.
// Tile BM x 128, 4 waves (2x2). LDS rows 32 shorts (64B), XOR-swizzled.
// ---------------------------------------------------------------------------
template<int BM, int KTOT>
__global__ __launch_bounds__(256)
void gemm_pairs_g(const int4* __restrict__ rowlist, int nrows_lit,
                  const int* __restrict__ nrows_ptr, int cap,
                  const unsigned short* __restrict__ h_hi,
                  const unsigned short* __restrict__ h_lo,
                  const unsigned short* __restrict__ w_hi,
                  const unsigned short* __restrict__ w_lo,
                  float* __restrict__ vbuf)
{
    constexpr int WROWS = BM / 2;
    constexpr int FM = WROWS / 16;
    constexpr int NRS = BM / 64;
    constexpr int SA = BM * 32;
    constexpr int SB = 128 * 32;
    constexpr int BUF = 2 * SA + 2 * SB;

    int nrows = nrows_ptr ? *nrows_ptr : nrows_lit;
    const int row0 = blockIdx.x * BM;
    if (row0 >= nrows) return;
    const int col0 = blockIdx.y * 128;
    const int kbeg = blockIdx.z * KTOT;
    const int kend = kbeg + KTOT;
    float* vout = vbuf + (size_t)blockIdx.z * cap * D5;

    const int tid = threadIdx.x, lane = tid & 63, w = tid >> 6;
    const int wm = w >> 1, wn = w & 1;

    __shared__ __align__(16) unsigned short smem[2 * BUF];

    const int sz8 = ((lane & 3) ^ ((lane >> 3) & 3)) * 8;
    size_t offL[NRS], offR[NRS];
#pragma unroll
    for (int rs = 0; rs < NRS; ++rs) {
        int rr = row0 + (w + 4 * rs) * 16 + (lane >> 2);
        if (rr > nrows - 1) rr = nrows - 1;
        int4 e = rowlist[rr];
        if (e.x < 0) { e.x = 0; e.y = 0; e.z = 1; }
        offL[rs] = ((size_t)(e.x * LM + e.y)) * D2;
        offR[rs] = ((size_t)(e.x * LM + e.z)) * D2;
    }
    size_t colOff[2];
#pragma unroll
    for (int cs = 0; cs < 2; ++cs)
        colOff[cs] = ((size_t)(col0 + (w + 4 * cs) * 16 + (lane >> 2))) * H4;

    auto stage = [&](int d, int k) {
        unsigned short* sb = smem + d * BUF;
#pragma unroll
        for (int j = 0; j < 2 * NRS; ++j) {
            const int pl = j / NRS, rs = j % NRS;
            const int g = w + 4 * rs;
            const unsigned short* hb = pl ? h_lo : h_hi;
            size_t off = (k < D2) ? (offL[rs] + k) : (offR[rs] + (k - D2));
            gload16(hb + off + sz8, sb + pl * SA + g * 512);
        }
#pragma unroll
        for (int j = 0; j < 4; ++j) {
            const int pl = j >> 1, cs = j & 1;
            const int g = w + 4 * cs;
            const unsigned short* wb = pl ? w_lo : w_hi;
            gload16(wb + colOff[cs] + k + sz8, sb + 2 * SA + pl * SB + g * 512);
        }
    };

    f32x4 acc[FM][4];
#pragma unroll
    for (int i = 0; i < FM; ++i)
#pragma unroll
        for (int j = 0; j < 4; ++j) acc[i][j] = (f32x4){0.f, 0.f, 0.f, 0.f};

    const int rsw = ((lane >> 4) ^ ((lane >> 1) & 3)) * 8;
    const int a_off = (wm * WROWS + (lane & 15)) * 32 + rsw;
    const int b_off = 2 * SA + (wn * 64 + (lane & 15)) * 32 + rsw;

    stage(0, kbeg);
    __syncthreads();
    int cur = 0;
    for (int k0 = kbeg; k0 < kend; k0 += 32) {
        if (k0 + 32 < kend) stage(cur ^ 1, k0 + 32);
        const unsigned short* sb = smem + cur * BUF;
        bf16x8 ah[FM], al[FM];
#pragma unroll
        for (int fm = 0; fm < FM; ++fm) {
            ah[fm] = *(const bf16x8*)&sb[a_off + fm * 512];
            al[fm] = *(const bf16x8*)&sb[SA + a_off + fm * 512];
        }
#pragma unroll
        for (int fn = 0; fn < 4; ++fn) {
            bf16x8 bh = *(const bf16x8*)&sb[b_off + fn * 512];
            bf16x8 bl = *(const bf16x8*)&sb[SB + b_off + fn * 512];
#pragma unroll
            for (int fm = 0; fm < FM; ++fm) {
                acc[fm][fn] = __builtin_amdgcn_mfma_f32_16x16x32_bf16(ah[fm], bh, acc[fm][fn], 0, 0, 0);
                acc[fm][fn] = __builtin_amdgcn_mfma_f32_16x16x32_bf16(ah[fm], bl, acc[fm][fn], 0, 0, 0);
                acc[fm][fn] = __builtin_amdgcn_mfma_f32_16x16x32_bf16(al[fm], bh, acc[fm][fn], 0, 0, 0);
            }
        }
        __syncthreads();
        cur ^= 1;
    }

#pragma unroll
    for (int fm = 0; fm < FM; ++fm) {
        int rbase = row0 + wm * WROWS + fm * 16 + (lane >> 4) * 4;
#pragma unroll
        for (int fn = 0; fn < 4; ++fn) {
            int c = col0 + wn * 64 + fn * 16 + (lane & 15);
#pragma unroll
            for (int q = 0; q < 4; ++q) {
                int r = rbase + q;
                if (r < nrows) vout[(size_t)r * D5 + c] = acc[fm][fn][q];
            }
        }
    }
}

// ---------------------------------------------------------------------------
__global__ __launch_bounds__(256)
void gates_logits(const int4* __restrict__ rowlist, int nrows_lit,
                  const int* __restrict__ nrows_ptr,
                  const float* __restrict__ v_buf, const float* __restrict__ v_buf2,
                  const float* __restrict__ b_comp,
                  const float* __restrict__ c_seq, const float* __restrict__ w_q,
                  float* __restrict__ nh_cand, float* __restrict__ nc_cand,
                  float* __restrict__ logits)
{
    int nrows = nrows_ptr ? *nrows_ptr : nrows_lit;
    int row = blockIdx.x;
    if (row >= nrows) return;
    int4 e = rowlist[row];
    if (e.x < 0) return;
    int b = e.x, sL = e.y, sR = e.z;
    int cslot = e.w & 0xffff, plog = e.w >> 16;
    const float* v = v_buf + (size_t)row * D5;
    const float* v2 = v_buf2 ? (v_buf2 + (size_t)row * D5) : nullptr;
    const float* cl = c_seq + ((size_t)(b * LM + sL)) * D2;
    const float* cr = c_seq + ((size_t)(b * LM + sR)) * D2;
    float* nh = nh_cand + ((size_t)(b * 15 + cslot)) * D2;
    float* nc = nc_cand + ((size_t)(b * 15 + cslot)) * D2;

    float part = 0.f;
    for (int d = threadIdx.x; d < D2; d += 256) {
        float gi  = v[d];
        float gfl = v[D2 + d];
        float gfr = v[2 * D2 + d];
        float gu  = v[3 * D2 + d];
        float go  = v[4 * D2 + d];
        if (v2) {
            gi += v2[d]; gfl += v2[D2 + d]; gfr += v2[2 * D2 + d];
            gu += v2[3 * D2 + d]; go += v2[4 * D2 + d];
        }
        gi += b_comp[d]; gfl += b_comp[D2 + d]; gfr += b_comp[2 * D2 + d];
        gu += b_comp[3 * D2 + d]; go += b_comp[4 * D2 + d];
        float c = cl[d] * sigm(gfl + 1.0f) + cr[d] * sigm(gfr + 1.0f) + tanhf(gu) * sigm(gi);
        float h = sigm(go) * tanhf(c);
        nc[d] = c; nh[d] = h;
        part += h * w_q[d];
    }
    for (int o = 32; o > 0; o >>= 1) part += __shfl_down(part, o);
    __shared__ float wsum[4];
    if ((threadIdx.x & 63) == 0) wsum[threadIdx.x >> 6] = part;
    __syncthreads();
    if (threadIdx.x == 0) logits[b * 16 + plog] = wsum[0] + wsum[1] + wsum[2] + wsum[3];
}

// ---------------------------------------------------------------------------
__global__ __launch_bounds__(256)
void merge_kernel(int iter, const int* __restrict__ lengths,
                  float* __restrict__ c_seq,
                  const float* __restrict__ nh_cand, const float* __restrict__ nc_cand,
                  float* __restrict__ logits, int* __restrict__ pos_idx,
                  int* __restrict__ pair_idx, int4* __restrict__ rowlist_out,
                  int* __restrict__ rcount,
                  unsigned short* __restrict__ h_hi, unsigned short* __restrict__ h_lo)
{
    int b = blockIdx.x, tid = threadIdx.x;
    int M = 15 - iter;
    int len = lengths[b];
    bool act = (iter + 1) < len;

    __shared__ float sl[16];
    __shared__ int sp[16], sq[16];
    __shared__ int s_sel;

    if (tid <= M) sp[tid] = pos_idx[b * 16 + tid];
    if (tid < M) { sq[tid] = pair_idx[b * 16 + tid]; sl[tid] = logits[b * 16 + tid]; }
    __syncthreads();

    if (tid == 0) {
        int sel = -1;
        if (act) {
            float best = -INFINITY; sel = 0;
            for (int p2 = 0; p2 < M; ++p2) {
                float mv = ((iter + 1 + p2) < len) ? sl[p2] : (sl[p2] - 10000.0f);
                if (mv > best) { best = mv; sel = p2; }
            }
        }
        s_sel = sel;
    }
    __syncthreads();
    int sel = s_sel;

    if (sel >= 0) {
        int slotL = sp[sel];
        int cslot = sq[sel];
        const float* nh = nh_cand + ((size_t)(b * 15 + cslot)) * D2;
        const float* nc = nc_cand + ((size_t)(b * 15 + cslot)) * D2;
        float* cd = c_seq + ((size_t)(b * LM + slotL)) * D2;
        unsigned short* hh = h_hi + ((size_t)(b * LM + slotL)) * D2;
        unsigned short* hl = h_lo + ((size_t)(b * LM + slotL)) * D2;
        for (int d = tid; d < D2; d += 256) {
            float hv = nh[d];
            cd[d] = nc[d];
            unsigned short hb = bf16_rne(hv);
            hh[d] = hb;
            hl[d] = bf16_rne(hv - bf16_tof(hb));
        }

        if (tid == 0) {
            for (int p2 = sel + 1; p2 < M; ++p2) sp[p2] = sp[p2 + 1];
            for (int p2 = sel + 1; p2 < M - 1; ++p2) { sq[p2] = sq[p2 + 1]; sl[p2] = sl[p2 + 1]; }
            int Mn = M - 1;
            if (iter < 14) {
                if (sel - 1 >= 0) {
                    int4 e0 = make_int4(b, sp[sel - 1], sp[sel], sq[sel - 1] | ((sel - 1) << 16));
                    int i0 = atomicAdd(rcount, 1);
                    rowlist_out[i0] = e0;
                }
                if (sel <= Mn - 1) {
                    int4 e1 = make_int4(b, sp[sel], sp[sel + 1], sq[sel] | (sel << 16));
                    int i1 = atomicAdd(rcount, 1);
                    rowlist_out[i1] = e1;
                }
            }
            for (int p2 = 0; p2 < M; ++p2) pos_idx[b * 16 + p2] = sp[p2];
            for (int p2 = 0; p2 < Mn; ++p2) { pair_idx[b * 16 + p2] = sq[p2]; logits[b * 16 + p2] = sl[p2]; }
        }
    }
}

__global__ __launch_bounds__(256)
void copy_out(const unsigned short* __restrict__ h_hi,
              const unsigned short* __restrict__ h_lo, float* __restrict__ out)
{
    int b = blockIdx.x;
    size_t base = (size_t)(b * LM) * D2;
    for (int d = threadIdx.x; d < D2; d += 256)
        out[(size_t)b * D2 + d] = bf16_tof(h_hi[base + d]) + bf16_tof(h_lo[base + d]);
}

// ---------------------------------------------------------------------------
extern "C" void kernel_launch(void* const* d_in, const int* in_sizes, int n_in,
                              void* d_out, int out_size, void* d_ws, size_t ws_size,
                              hipStream_t stream)
{
    const float* x      = (const float*)d_in[0];
    const int*   lens   = (const int*)  d_in[1];
    const float* w_ih_f = (const float*)d_in[2];
    const float* w_hh_f = (const float*)d_in[3];
    const float* b_f    = (const float*)d_in[4];
    const float* w_ih_b = (const float*)d_in[5];
    const float* w_hh_b = (const float*)d_in[6];
    const float* b_b    = (const float*)d_in[7];
    const float* w_comp = (const float*)d_in[8];
    const float* b_comp = (const float*)d_in[9];
    const float* w_q    = (const float*)d_in[10];
    float* out = (float*)d_out;

    char* p = (char*)d_ws;
    auto alloc = [&](size_t bytes) {
        char* q = p; p += (bytes + 255) & ~(size_t)255; return q;
    };
    float* c_seq = (float*)alloc((size_t)NB * LM * D2 * 4);
    float* nh    = (float*)alloc((size_t)NB * 15 * D2 * 4);
    float* nc    = (float*)alloc((size_t)NB * 15 * D2 * 4);
    unsigned short* h_hi = (unsigned short*)alloc((size_t)NB * LM * D2 * 2);
    unsigned short* h_lo = (unsigned short*)alloc((size_t)NB * LM * D2 * 2);
    unsigned short* w_hi = (unsigned short*)alloc((size_t)D5 * H4 * 2);
    unsigned short* w_lo = (unsigned short*)alloc((size_t)D5 * H4 * 2);
    unsigned short* x_hi = (unsigned short*)alloc((size_t)NB * LM * HID * 2);
    unsigned short* x_lo = (unsigned short*)alloc((size_t)NB * LM * HID * 2);
    unsigned short* wl_hi = (unsigned short*)alloc((size_t)2 * H4 * 1024 * 2);
    unsigned short* wl_lo = (unsigned short*)alloc((size_t)2 * H4 * 1024 * 2);
    unsigned short* hc_hi = (unsigned short*)alloc((size_t)2 * NB * HID * 2);
    unsigned short* hc_lo = (unsigned short*)alloc((size_t)2 * NB * HID * 2);
    float* ccur  = (float*)alloc((size_t)2 * NB * HID * 4);
    float* logits = (float*)alloc((size_t)NB * 16 * 4);
    int*   pos    = (int*)alloc((size_t)NB * 16 * 4);
    int*   pair   = (int*)alloc((size_t)NB * 16 * 4);
    int4*  rowlist0   = (int4*)alloc((size_t)NPAIR0 * 16);
    int4*  rowlist_c  = (int4*)alloc((size_t)NPAIR0 * 16);
    int4*  rowlist_inc= (int4*)alloc((size_t)INC_CAP * 16);
    int*   rcount = (int*)alloc(16 * 4);
    // tail: gbuf (LSTM, 4.2MB) then reused as vbuf (pairs)
    char* tail = p;
    float* gbuf = (float*)tail;
    float* vbuf = (float*)tail;

    size_t used = (size_t)(tail - (char*)d_ws);
    size_t avail = (ws_size > used) ? (ws_size - used) : 0;
    size_t maxc = avail / ((size_t)D5 * 4);
    if (maxc > (size_t)NPAIR0) maxc = NPAIR0;
    int chunk = ((int)maxc) & ~127;
    if (chunk < 1024) chunk = 1024;

    hipMemsetAsync(rcount, 0, 64, stream);
    init_kernel<<<dim3(NB), dim3(256), 0, stream>>>(lens, ccur, hc_hi, hc_lo, pos, pair,
                                                    rowlist0, rowlist_c, rcount, logits);
    split_w<<<dim3(2048), dim3(256), 0, stream>>>((const float4*)w_comp, w_hi, w_lo, (int)((size_t)D5 * H4 / 4));
    split_w<<<dim3(1024), dim3(256), 0, stream>>>((const float4*)x, x_hi, x_lo, (int)((size_t)NB * LM * HID / 4));
    pack_lstm_w<<<dim3(1024), dim3(256), 0, stream>>>(w_ih_f, w_hh_f, w_ih_b, w_hh_b, wl_hi, wl_lo);

    // ---- bidirectional LSTM, 16 sequential steps ----
    for (int t = 0; t < 16; ++t) {
        gemm_lstm_g<<<dim3(4, 16, 2), dim3(256), 0, stream>>>(
            t, lens, x_hi, x_lo, hc_hi, hc_lo, wl_hi, wl_lo, gbuf);
        lstm_gate<<<dim3(NB, 2), dim3(256), 0, stream>>>(
            t, lens, b_f, b_b, gbuf, ccur, hc_hi, hc_lo, h_hi, h_lo, c_seq);
    }

    // ---- iter 0: candidates + logits (length-compacted if vbuf fits) ----
    if (chunk >= NPAIR0) {
        gemm_pairs_g<128, 2048><<<dim3(30, 40, 1), dim3(256), 0, stream>>>(
            rowlist_c, NPAIR0, (const int*)(rcount + 14), 0,
            h_hi, h_lo, w_hi, w_lo, vbuf);
        gates_logits<<<dim3(NPAIR0), dim3(256), 0, stream>>>(
            rowlist_c, NPAIR0, (const int*)(rcount + 14),
            vbuf, (const float*)nullptr, b_comp, c_seq, w_q, nh, nc, logits);
    } else {
        for (int off = 0; off < NPAIR0; off += chunk) {
            int rows = NPAIR0 - off; if (rows > chunk) rows = chunk;
            int RT = (rows + 127) >> 7;
            gemm_pairs_g<128, 2048><<<dim3(RT, 40, 1), dim3(256), 0, stream>>>(
                rowlist0 + off, rows, (const int*)nullptr, 0,
                h_hi, h_lo, w_hi, w_lo, vbuf);
            gates_logits<<<dim3(rows), dim3(256), 0, stream>>>(
                rowlist0 + off, rows, (const int*)nullptr,
                vbuf, (const float*)nullptr, b_comp, c_seq, w_q, nh, nc, logits);
        }
    }

    // ---- 14 selection iterations (compacted incremental, split-K x2) ----
    float* vbuf2 = vbuf + (size_t)INC_CAP * D5;
    for (int it = 0; it < 14; ++it) {
        merge_kernel<<<dim3(NB), dim3(256), 0, stream>>>(
            it, lens, c_seq, nh, nc, logits, pos, pair,
            rowlist_inc, rcount + it, h_hi, h_lo);
        gemm_pairs_g<128, 1024><<<dim3(4, 40, 2), dim3(256), 0, stream>>>(
            rowlist_inc, 0, (const int*)(rcount + it), INC_CAP,
            h_hi, h_lo, w_hi, w_lo, vbuf);
        gates_logits<<<dim3(INC_CAP), dim3(256), 0, stream>>>(
            rowlist_inc, 0, (const int*)(rcount + it),
            vbuf, vbuf2, b_comp, c_seq, w_q, nh, nc, logits);
    }
    merge_kernel<<<dim3(NB), dim3(256), 0, stream>>>(
        14, lens, c_seq, nh, nc, logits, pos, pair,
        rowlist_inc, rcount + 15, h_hi, h_lo);

    copy_out<<<dim3(NB), dim3(256), 0, stream>>>(h_hi, h_lo, out);
}

// Round 8
// 1405.273 us; speedup vs baseline: 4.1144x; 1.0650x over previous
//
#include <hip/hip_runtime.h>
#include <math.h>

#define NB 256
#define LM 16
#define HID 512
#define H4 2048
#define D2 1024
#define D5 5120
#define NPAIR0 3840   // 256*15
#define INC_CAP 512   // max incremental rows (2 per batch)

typedef __attribute__((ext_vector_type(8))) short bf16x8;
typedef __attribute__((ext_vector_type(4))) float f32x4;

__device__ __forceinline__ float sigm(float x) { return 1.0f / (1.0f + expf(-x)); }

__device__ __forceinline__ unsigned short bf16_rne(float f) {
    union { float f; unsigned u; } v; v.f = f;
    unsigned u = v.u;
    return (unsigned short)((u + 0x7fffu + ((u >> 16) & 1u)) >> 16);
}
__device__ __forceinline__ float bf16_tof(unsigned short h) {
    union { unsigned u; float f; } v; v.u = ((unsigned)h) << 16;
    return v.f;
}

// async global->LDS, 16B per lane; dest = wave-uniform base + lane*16
__device__ __forceinline__ void gload16(const unsigned short* g, unsigned short* l) {
    __builtin_amdgcn_global_load_lds(
        (const __attribute__((address_space(1))) void*)(const void*)g,
        (__attribute__((address_space(3))) void*)(void*)l, 16, 0, 0);
}

// ---------------------------------------------------------------------------
// init: zero LSTM state, slot maps, uncompacted + length-compacted rowlists,
// logits = -1e30 (missing pairs stay masked). rcount must be pre-zeroed.
// ---------------------------------------------------------------------------
__global__ __launch_bounds__(256)
void init_kernel(const int* __restrict__ lens, float* ccur,
                 unsigned short* hc_hi, unsigned short* hc_lo,
                 int* pos, int* pair, int4* rowlist0, int4* rowlist_c,
                 int* rcount, float* logits)
{
    int b = blockIdx.x, tid = threadIdx.x;
    for (int u = tid; u < HID; u += 256) {
        ccur[(size_t)b * HID + u] = 0.f;
        ccur[((size_t)NB + b) * HID + u] = 0.f;
        hc_hi[(size_t)b * HID + u] = 0;
        hc_hi[((size_t)NB + b) * HID + u] = 0;
        hc_lo[(size_t)b * HID + u] = 0;
        hc_lo[((size_t)NB + b) * HID + u] = 0;
    }
    if (tid < 16) { pos[b * 16 + tid] = tid; pair[b * 16 + tid] = tid; logits[b * 16 + tid] = -1e30f; }
    if (tid < 15) rowlist0[b * 15 + tid] = make_int4(b, tid, tid + 1, tid | (tid << 16));
    __shared__ int sbase;
    int len = lens[b];
    if (tid == 0) sbase = atomicAdd(rcount + 14, len - 1);
    __syncthreads();
    if (tid < len - 1) rowlist_c[sbase + tid] = make_int4(b, tid, tid + 1, tid | (tid << 16));
}

// ---------------------------------------------------------------------------
__global__ __launch_bounds__(256)
void split_w(const float4* __restrict__ w, unsigned short* __restrict__ hi,
             unsigned short* __restrict__ lo, int n4)
{
    for (int i = blockIdx.x * 256 + threadIdx.x; i < n4; i += gridDim.x * 256) {
        float4 f = w[i];
        ushort4 h, l;
        h.x = bf16_rne(f.x); l.x = bf16_rne(f.x - bf16_tof(h.x));
        h.y = bf16_rne(f.y); l.y = bf16_rne(f.y - bf16_tof(h.y));
        h.z = bf16_rne(f.z); l.z = bf16_rne(f.z - bf16_tof(h.z));
        h.w = bf16_rne(f.w); l.w = bf16_rne(f.w - bf16_tof(h.w));
        ((ushort4*)hi)[i] = h;
        ((ushort4*)lo)[i] = l;
    }
}

// ---------------------------------------------------------------------------
__global__ __launch_bounds__(256)
void pack_lstm_w(const float* __restrict__ w_ih_f, const float* __restrict__ w_hh_f,
                 const float* __restrict__ w_ih_b, const float* __restrict__ w_hh_b,
                 unsigned short* __restrict__ wl_hi, unsigned short* __restrict__ wl_lo)
{
    const int total4 = 2 * H4 * 256;
    for (int i = blockIdx.x * 256 + threadIdx.x; i < total4; i += gridDim.x * 256) {
        int k4 = i & 255;
        int j = (i >> 8) & 2047;
        int dir = i >> 19;
        const float* wih = dir ? w_ih_b : w_ih_f;
        const float* whh = dir ? w_hh_b : w_hh_f;
        float4 f = (k4 < 128) ? *(const float4*)(wih + (size_t)j * HID + k4 * 4)
                              : *(const float4*)(whh + (size_t)j * HID + (k4 - 128) * 4);
        ushort4 h, l;
        h.x = bf16_rne(f.x); l.x = bf16_rne(f.x - bf16_tof(h.x));
        h.y = bf16_rne(f.y); l.y = bf16_rne(f.y - bf16_tof(h.y));
        h.z = bf16_rne(f.z); l.z = bf16_rne(f.z - bf16_tof(h.z));
        h.w = bf16_rne(f.w); l.w = bf16_rne(f.w - bf16_tof(h.w));
        ((ushort4*)wl_hi)[i] = h;
        ((ushort4*)wl_lo)[i] = l;
    }
}

// ---------------------------------------------------------------------------
// LSTM step GEMM: gload_lds staging, double-buffered LDS, swizzled.
// Split-K x2: blockIdx.z = dir + 2*kz; kz=0 -> x.W_ih (k in [0,512)),
// kz=1 -> h.W_hh (k in [512,1024)). Partial to gbuf + kz*2*NB*H4.
// ---------------------------------------------------------------------------
__global__ __launch_bounds__(256)
void gemm_lstm_g(int t, const int* __restrict__ lens,
                 const unsigned short* __restrict__ x_hi, const unsigned short* __restrict__ x_lo,
                 const unsigned short* __restrict__ hc_hi, const unsigned short* __restrict__ hc_lo,
                 const unsigned short* __restrict__ wl_hi, const unsigned short* __restrict__ wl_lo,
                 float* __restrict__ gbuf)
{
    constexpr int SA = 64 * 32;        // shorts per A plane
    constexpr int SB = 128 * 32;       // shorts per B plane
    constexpr int BUF = 2 * SA + 2 * SB;

    const int row0 = blockIdx.x * 64;
    const int col0 = blockIdx.y * 128;
    const int dir = blockIdx.z & 1;
    const int kz = blockIdx.z >> 1;
    const int kbeg = kz * 512, kend = kbeg + 512;
    float* gout = gbuf + (size_t)kz * 2 * NB * H4;

    const int tid = threadIdx.x, lane = tid & 63, w = tid >> 6;
    const int wm = w >> 1, wn = w & 1;

    __shared__ __align__(16) unsigned short smem[2 * BUF];

    const int sz8 = ((lane & 3) ^ ((lane >> 3) & 3)) * 8;  // swizzled source part
    const int b0 = row0 + w * 16 + (lane >> 2);
    const int len = lens[b0];
    const int trow = dir ? ((t < len) ? (len - 1 - t) : t) : t;
    const size_t xoff = ((size_t)(b0 * LM + trow)) * HID;
    const size_t hoff = ((size_t)(dir * NB + b0)) * HID;

    size_t colOff[2];
#pragma unroll
    for (int cs = 0; cs < 2; ++cs)
        colOff[cs] = ((size_t)(dir * H4 + col0 + (w + 4 * cs) * 16 + (lane >> 2))) * 1024;

    auto stage = [&](int d, int k) {
        unsigned short* sb = smem + d * BUF;
        const unsigned short* sh = (k < HID) ? (x_hi + xoff + k) : (hc_hi + hoff + (k - HID));
        gload16(sh + sz8, sb + w * 512);
        const unsigned short* sl = (k < HID) ? (x_lo + xoff + k) : (hc_lo + hoff + (k - HID));
        gload16(sl + sz8, sb + SA + w * 512);
#pragma unroll
        for (int j = 0; j < 4; ++j) {
            const int pl = j >> 1, cs = j & 1;
            const unsigned short* wb = pl ? wl_lo : wl_hi;
            gload16(wb + colOff[cs] + k + sz8, sb + 2 * SA + pl * SB + (w + 4 * cs) * 512);
        }
    };

    f32x4 acc[2][4];
#pragma unroll
    for (int i = 0; i < 2; ++i)
#pragma unroll
        for (int j = 0; j < 4; ++j) acc[i][j] = (f32x4){0.f, 0.f, 0.f, 0.f};

    const int rsw = ((lane >> 4) ^ ((lane >> 1) & 3)) * 8;   // swizzled read slot
    const int a_off = (wm * 32 + (lane & 15)) * 32 + rsw;
    const int b_off = 2 * SA + (wn * 64 + (lane & 15)) * 32 + rsw;

    stage(0, kbeg);
    __syncthreads();
    int cur = 0;
    for (int k0 = kbeg; k0 < kend; k0 += 32) {
        if (k0 + 32 < kend) stage(cur ^ 1, k0 + 32);
        const unsigned short* sb = smem + cur * BUF;
        bf16x8 ah[2], al[2];
#pragma unroll
        for (int fm = 0; fm < 2; ++fm) {
            ah[fm] = *(const bf16x8*)&sb[a_off + fm * 512];
            al[fm] = *(const bf16x8*)&sb[SA + a_off + fm * 512];
        }
#pragma unroll
        for (int fn = 0; fn < 4; ++fn) {
            bf16x8 bh = *(const bf16x8*)&sb[b_off + fn * 512];
            bf16x8 bl = *(const bf16x8*)&sb[SB + b_off + fn * 512];
#pragma unroll
            for (int fm = 0; fm < 2; ++fm) {
                acc[fm][fn] = __builtin_amdgcn_mfma_f32_16x16x32_bf16(ah[fm], bh, acc[fm][fn], 0, 0, 0);
                acc[fm][fn] = __builtin_amdgcn_mfma_f32_16x16x32_bf16(ah[fm], bl, acc[fm][fn], 0, 0, 0);
                acc[fm][fn] = __builtin_amdgcn_mfma_f32_16x16x32_bf16(al[fm], bh, acc[fm][fn], 0, 0, 0);
            }
        }
        __syncthreads();
        cur ^= 1;
    }

#pragma unroll
    for (int fm = 0; fm < 2; ++fm) {
        int rbase = row0 + wm * 32 + fm * 16 + (lane >> 4) * 4;
#pragma unroll
        for (int fn = 0; fn < 4; ++fn) {
            int c = col0 + wn * 64 + fn * 16 + (lane & 15);
#pragma unroll
            for (int q = 0; q < 4; ++q)
                gout[((size_t)(dir * NB + rbase + q)) * H4 + c] = acc[fm][fn][q];
        }
    }
}

// ---------------------------------------------------------------------------
__global__ __launch_bounds__(256)
void lstm_gate(int t, const int* __restrict__ lengths,
               const float* __restrict__ b_f, const float* __restrict__ b_b,
               const float* __restrict__ g_buf, float* __restrict__ ccur,
               unsigned short* __restrict__ hc_hi, unsigned short* __restrict__ hc_lo,
               unsigned short* __restrict__ h_hi, unsigned short* __restrict__ h_lo,
               float* __restrict__ c_seq)
{
    int b = blockIdx.x, dir = blockIdx.y, tid = threadIdx.x;
    const float* bias = dir ? b_b : b_f;
    int len = lengths[b];
    int pos = dir ? ((t < len) ? (len - 1 - t) : t) : t;
    const float* g0 = g_buf + ((size_t)(dir * NB + b)) * H4;
    const float* g1 = g0 + (size_t)2 * NB * H4;
    float* cc = ccur + ((size_t)(dir * NB + b)) * HID;
    unsigned short* hch = hc_hi + ((size_t)(dir * NB + b)) * HID;
    unsigned short* hcl = hc_lo + ((size_t)(dir * NB + b)) * HID;
    size_t so = ((size_t)(b * LM + pos)) * D2 + dir * HID;
    for (int u = tid; u < HID; u += 256) {
        float gi = g0[u]           + g1[u]           + bias[u];
        float gf = g0[HID + u]     + g1[HID + u]     + bias[HID + u];
        float gu = g0[2 * HID + u] + g1[2 * HID + u] + bias[2 * HID + u];
        float go = g0[3 * HID + u] + g1[3 * HID + u] + bias[3 * HID + u];
        float c = sigm(gf) * cc[u] + sigm(gi) * tanhf(gu);
        float h = sigm(go) * tanhf(c);
        cc[u] = c; c_seq[so + u] = c;
        unsigned short hb = bf16_rne(h);
        unsigned short hl2 = bf16_rne(h - bf16_tof(hb));
        hch[u] = hb; hcl[u] = hl2;
        h_hi[so + u] = hb; h_lo[so + u] = hl2;
    }
}

// ---------------------------------------------------------------------------
// Pair GEMM: gload_lds staging, double-buffered LDS, 1 barrier/K-step.
// Tile BM x 128, 4 waves (2x2). LDS rows 32 shorts (64B), XOR-swizzled.
// ---------------------------------------------------------------------------
template<int BM, int KTOT>
__global__ __launch_bounds__(256)
void gemm_pairs_g(const int4* __restrict__ rowlist, int nrows_lit,
                  const int* __restrict__ nrows_ptr, int cap,
                  const unsigned short* __restrict__ h_hi,
                  const unsigned short* __restrict__ h_lo,
                  const unsigned short* __restrict__ w_hi,
                  const unsigned short* __restrict__ w_lo,
                  float* __restrict__ vbuf)
{
    constexpr int WROWS = BM / 2;
    constexpr int FM = WROWS / 16;
    constexpr int NRS = BM / 64;
    constexpr int SA = BM * 32;
    constexpr int SB = 128 * 32;
    constexpr int BUF = 2 * SA + 2 * SB;

    int nrows = nrows_ptr ? *nrows_ptr : nrows_lit;
    const int row0 = blockIdx.x * BM;
    if (row0 >= nrows) return;
    const int col0 = blockIdx.y * 128;
    const int kbeg = blockIdx.z * KTOT;
    const int kend = kbeg + KTOT;
    float* vout = vbuf + (size_t)blockIdx.z * cap * D5;

    const int tid = threadIdx.x, lane = tid & 63, w = tid >> 6;
    const int wm = w >> 1, wn = w & 1;

    __shared__ __align__(16) unsigned short smem[2 * BUF];

    const int sz8 = ((lane & 3) ^ ((lane >> 3) & 3)) * 8;
    size_t offL[NRS], offR[NRS];
#pragma unroll
    for (int rs = 0; rs < NRS; ++rs) {
        int rr = row0 + (w + 4 * rs) * 16 + (lane >> 2);
        if (rr > nrows - 1) rr = nrows - 1;
        int4 e = rowlist[rr];
        if (e.x < 0) { e.x = 0; e.y = 0; e.z = 1; }
        offL[rs] = ((size_t)(e.x * LM + e.y)) * D2;
        offR[rs] = ((size_t)(e.x * LM + e.z)) * D2;
    }
    size_t colOff[2];
#pragma unroll
    for (int cs = 0; cs < 2; ++cs)
        colOff[cs] = ((size_t)(col0 + (w + 4 * cs) * 16 + (lane >> 2))) * H4;

    auto stage = [&](int d, int k) {
        unsigned short* sb = smem + d * BUF;
#pragma unroll
        for (int j = 0; j < 2 * NRS; ++j) {
            const int pl = j / NRS, rs = j % NRS;
            const int g = w + 4 * rs;
            const unsigned short* hb = pl ? h_lo : h_hi;
            size_t off = (k < D2) ? (offL[rs] + k) : (offR[rs] + (k - D2));
            gload16(hb + off + sz8, sb + pl * SA + g * 512);
        }
#pragma unroll
        for (int j = 0; j < 4; ++j) {
            const int pl = j >> 1, cs = j & 1;
            const int g = w + 4 * cs;
            const unsigned short* wb = pl ? w_lo : w_hi;
            gload16(wb + colOff[cs] + k + sz8, sb + 2 * SA + pl * SB + g * 512);
        }
    };

    f32x4 acc[FM][4];
#pragma unroll
    for (int i = 0; i < FM; ++i)
#pragma unroll
        for (int j = 0; j < 4; ++j) acc[i][j] = (f32x4){0.f, 0.f, 0.f, 0.f};

    const int rsw = ((lane >> 4) ^ ((lane >> 1) & 3)) * 8;
    const int a_off = (wm * WROWS + (lane & 15)) * 32 + rsw;
    const int b_off = 2 * SA + (wn * 64 + (lane & 15)) * 32 + rsw;

    stage(0, kbeg);
    __syncthreads();
    int cur = 0;
    for (int k0 = kbeg; k0 < kend; k0 += 32) {
        if (k0 + 32 < kend) stage(cur ^ 1, k0 + 32);
        const unsigned short* sb = smem + cur * BUF;
        bf16x8 ah[FM], al[FM];
#pragma unroll
        for (int fm = 0; fm < FM; ++fm) {
            ah[fm] = *(const bf16x8*)&sb[a_off + fm * 512];
            al[fm] = *(const bf16x8*)&sb[SA + a_off + fm * 512];
        }
#pragma unroll
        for (int fn = 0; fn < 4; ++fn) {
            bf16x8 bh = *(const bf16x8*)&sb[b_off + fn * 512];
            bf16x8 bl = *(const bf16x8*)&sb[SB + b_off + fn * 512];
#pragma unroll
            for (int fm = 0; fm < FM; ++fm) {
                acc[fm][fn] = __builtin_amdgcn_mfma_f32_16x16x32_bf16(ah[fm], bh, acc[fm][fn], 0, 0, 0);
                acc[fm][fn] = __builtin_amdgcn_mfma_f32_16x16x32_bf16(ah[fm], bl, acc[fm][fn], 0, 0, 0);
                acc[fm][fn] = __builtin_amdgcn_mfma_f32_16x16x32_bf16(al[fm], bh, acc[fm][fn], 0, 0, 0);
            }
        }
        __syncthreads();
        cur ^= 1;
    }

#pragma unroll
    for (int fm = 0; fm < FM; ++fm) {
        int rbase = row0 + wm * WROWS + fm * 16 + (lane >> 4) * 4;
#pragma unroll
        for (int fn = 0; fn < 4; ++fn) {
            int c = col0 + wn * 64 + fn * 16 + (lane & 15);
#pragma unroll
            for (int q = 0; q < 4; ++q) {
                int r = rbase + q;
                if (r < nrows) vout[(size_t)r * D5 + c] = acc[fm][fn][q];
            }
        }
    }
}

// ---------------------------------------------------------------------------
// TreeLSTM gates + logit. Sums nz split-K partials (vbuf + z*cap*D5).
// ---------------------------------------------------------------------------
__global__ __launch_bounds__(256)
void gates_logits(const int4* __restrict__ rowlist, int nrows_lit,
                  const int* __restrict__ nrows_ptr,
                  const float* __restrict__ v_buf, int cap, int nz,
                  const float* __restrict__ b_comp,
                  const float* __restrict__ c_seq, const float* __restrict__ w_q,
                  float* __restrict__ nh_cand, float* __restrict__ nc_cand,
                  float* __restrict__ logits)
{
    int nrows = nrows_ptr ? *nrows_ptr : nrows_lit;
    int row = blockIdx.x;
    if (row >= nrows) return;
    int4 e = rowlist[row];
    if (e.x < 0) return;
    int b = e.x, sL = e.y, sR = e.z;
    int cslot = e.w & 0xffff, plog = e.w >> 16;
    const float* v = v_buf + (size_t)row * D5;
    const size_t zstride = (size_t)cap * D5;
    const float* cl = c_seq + ((size_t)(b * LM + sL)) * D2;
    const float* cr = c_seq + ((size_t)(b * LM + sR)) * D2;
    float* nh = nh_cand + ((size_t)(b * 15 + cslot)) * D2;
    float* nc = nc_cand + ((size_t)(b * 15 + cslot)) * D2;

    float part = 0.f;
    for (int d = threadIdx.x; d < D2; d += 256) {
        float gi  = v[d];
        float gfl = v[D2 + d];
        float gfr = v[2 * D2 + d];
        float gu  = v[3 * D2 + d];
        float go  = v[4 * D2 + d];
        for (int z = 1; z < nz; ++z) {
            const float* vz = v + z * zstride;
            gi += vz[d]; gfl += vz[D2 + d]; gfr += vz[2 * D2 + d];
            gu += vz[3 * D2 + d]; go += vz[4 * D2 + d];
        }
        gi += b_comp[d]; gfl += b_comp[D2 + d]; gfr += b_comp[2 * D2 + d];
        gu += b_comp[3 * D2 + d]; go += b_comp[4 * D2 + d];
        float c = cl[d] * sigm(gfl + 1.0f) + cr[d] * sigm(gfr + 1.0f) + tanhf(gu) * sigm(gi);
        float h = sigm(go) * tanhf(c);
        nc[d] = c; nh[d] = h;
        part += h * w_q[d];
    }
    for (int o = 32; o > 0; o >>= 1) part += __shfl_down(part, o);
    __shared__ float wsum[4];
    if ((threadIdx.x & 63) == 0) wsum[threadIdx.x >> 6] = part;
    __syncthreads();
    if (threadIdx.x == 0) logits[b * 16 + plog] = wsum[0] + wsum[1] + wsum[2] + wsum[3];
}

// ---------------------------------------------------------------------------
__global__ __launch_bounds__(256)
void merge_kernel(int iter, const int* __restrict__ lengths,
                  float* __restrict__ c_seq,
                  const float* __restrict__ nh_cand, const float* __restrict__ nc_cand,
                  float* __restrict__ logits, int* __restrict__ pos_idx,
                  int* __restrict__ pair_idx, int4* __restrict__ rowlist_out,
                  int* __restrict__ rcount,
                  unsigned short* __restrict__ h_hi, unsigned short* __restrict__ h_lo)
{
    int b = blockIdx.x, tid = threadIdx.x;
    int M = 15 - iter;
    int len = lengths[b];
    bool act = (iter + 1) < len;

    __shared__ float sl[16];
    __shared__ int sp[16], sq[16];
    __shared__ int s_sel;

    if (tid <= M) sp[tid] = pos_idx[b * 16 + tid];
    if (tid < M) { sq[tid] = pair_idx[b * 16 + tid]; sl[tid] = logits[b * 16 + tid]; }
    __syncthreads();

    if (tid == 0) {
        int sel = -1;
        if (act) {
            float best = -INFINITY; sel = 0;
            for (int p2 = 0; p2 < M; ++p2) {
                float mv = ((iter + 1 + p2) < len) ? sl[p2] : (sl[p2] - 10000.0f);
                if (mv > best) { best = mv; sel = p2; }
            }
        }
        s_sel = sel;
    }
    __syncthreads();
    int sel = s_sel;

    if (sel >= 0) {
        int slotL = sp[sel];
        int cslot = sq[sel];
        const float* nh = nh_cand + ((size_t)(b * 15 + cslot)) * D2;
        const float* nc = nc_cand + ((size_t)(b * 15 + cslot)) * D2;
        float* cd = c_seq + ((size_t)(b * LM + slotL)) * D2;
        unsigned short* hh = h_hi + ((size_t)(b * LM + slotL)) * D2;
        unsigned short* hl = h_lo + ((size_t)(b * LM + slotL)) * D2;
        for (int d = tid; d < D2; d += 256) {
            float hv = nh[d];
            cd[d] = nc[d];
            unsigned short hb = bf16_rne(hv);
            hh[d] = hb;
            hl[d] = bf16_rne(hv - bf16_tof(hb));
        }

        if (tid == 0) {
            for (int p2 = sel + 1; p2 < M; ++p2) sp[p2] = sp[p2 + 1];
            for (int p2 = sel + 1; p2 < M - 1; ++p2) { sq[p2] = sq[p2 + 1]; sl[p2] = sl[p2 + 1]; }
            int Mn = M - 1;
            if (iter < 14) {
                if (sel - 1 >= 0) {
                    int4 e0 = make_int4(b, sp[sel - 1], sp[sel], sq[sel - 1] | ((sel - 1) << 16));
                    int i0 = atomicAdd(rcount, 1);
                    rowlist_out[i0] = e0;
                }
                if (sel <= Mn - 1) {
                    int4 e1 = make_int4(b, sp[sel], sp[sel + 1], sq[sel] | (sel << 16));
                    int i1 = atomicAdd(rcount, 1);
                    rowlist_out[i1] = e1;
                }
            }
            for (int p2 = 0; p2 < M; ++p2) pos_idx[b * 16 + p2] = sp[p2];
            for (int p2 = 0; p2 < Mn; ++p2) { pair_idx[b * 16 + p2] = sq[p2]; logits[b * 16 + p2] = sl[p2]; }
        }
    }
}

__global__ __launch_bounds__(256)
void copy_out(const unsigned short* __restrict__ h_hi,
              const unsigned short* __restrict__ h_lo, float* __restrict__ out)
{
    int b = blockIdx.x;
    size_t base = (size_t)(b * LM) * D2;
    for (int d = threadIdx.x; d < D2; d += 256)
        out[(size_t)b * D2 + d] = bf16_tof(h_hi[base + d]) + bf16_tof(h_lo[base + d]);
}

// ---------------------------------------------------------------------------
extern "C" void kernel_launch(void* const* d_in, const int* in_sizes, int n_in,
                              void* d_out, int out_size, void* d_ws, size_t ws_size,
                              hipStream_t stream)
{
    const float* x      = (const float*)d_in[0];
    const int*   lens   = (const int*)  d_in[1];
    const float* w_ih_f = (const float*)d_in[2];
    const float* w_hh_f = (const float*)d_in[3];
    const float* b_f    = (const float*)d_in[4];
    const float* w_ih_b = (const float*)d_in[5];
    const float* w_hh_b = (const float*)d_in[6];
    const float* b_b    = (const float*)d_in[7];
    const float* w_comp = (const float*)d_in[8];
    const float* b_comp = (const float*)d_in[9];
    const float* w_q    = (const float*)d_in[10];
    float* out = (float*)d_out;

    char* p = (char*)d_ws;
    auto alloc = [&](size_t bytes) {
        char* q = p; p += (bytes + 255) & ~(size_t)255; return q;
    };
    float* c_seq = (float*)alloc((size_t)NB * LM * D2 * 4);
    float* nh    = (float*)alloc((size_t)NB * 15 * D2 * 4);
    float* nc    = (float*)alloc((size_t)NB * 15 * D2 * 4);
    unsigned short* h_hi = (unsigned short*)alloc((size_t)NB * LM * D2 * 2);
    unsigned short* h_lo = (unsigned short*)alloc((size_t)NB * LM * D2 * 2);
    unsigned short* w_hi = (unsigned short*)alloc((size_t)D5 * H4 * 2);
    unsigned short* w_lo = (unsigned short*)alloc((size_t)D5 * H4 * 2);
    unsigned short* x_hi = (unsigned short*)alloc((size_t)NB * LM * HID * 2);
    unsigned short* x_lo = (unsigned short*)alloc((size_t)NB * LM * HID * 2);
    unsigned short* wl_hi = (unsigned short*)alloc((size_t)2 * H4 * 1024 * 2);
    unsigned short* wl_lo = (unsigned short*)alloc((size_t)2 * H4 * 1024 * 2);
    unsigned short* hc_hi = (unsigned short*)alloc((size_t)2 * NB * HID * 2);
    unsigned short* hc_lo = (unsigned short*)alloc((size_t)2 * NB * HID * 2);
    float* ccur  = (float*)alloc((size_t)2 * NB * HID * 4);
    float* logits = (float*)alloc((size_t)NB * 16 * 4);
    int*   pos    = (int*)alloc((size_t)NB * 16 * 4);
    int*   pair   = (int*)alloc((size_t)NB * 16 * 4);
    int4*  rowlist0   = (int4*)alloc((size_t)NPAIR0 * 16);
    int4*  rowlist_c  = (int4*)alloc((size_t)NPAIR0 * 16);
    int4*  rowlist_inc= (int4*)alloc((size_t)INC_CAP * 16);
    int*   rcount = (int*)alloc(16 * 4);
    // tail: gbuf (LSTM partials, 8.4MB) then reused as vbuf (pairs)
    char* tail = p;
    float* gbuf = (float*)tail;
    float* vbuf = (float*)tail;

    size_t used = (size_t)(tail - (char*)d_ws);
    size_t avail = (ws_size > used) ? (ws_size - used) : 0;
    size_t maxc = avail / ((size_t)D5 * 4);
    if (maxc > (size_t)NPAIR0) maxc = NPAIR0;
    int chunk = ((int)maxc) & ~127;
    if (chunk < 2048) chunk = 2048;   // need >= 4*INC_CAP rows of vbuf anyway

    hipMemsetAsync(rcount, 0, 64, stream);
    init_kernel<<<dim3(NB), dim3(256), 0, stream>>>(lens, ccur, hc_hi, hc_lo, pos, pair,
                                                    rowlist0, rowlist_c, rcount, logits);
    split_w<<<dim3(2048), dim3(256), 0, stream>>>((const float4*)w_comp, w_hi, w_lo, (int)((size_t)D5 * H4 / 4));
    split_w<<<dim3(1024), dim3(256), 0, stream>>>((const float4*)x, x_hi, x_lo, (int)((size_t)NB * LM * HID / 4));
    pack_lstm_w<<<dim3(1024), dim3(256), 0, stream>>>(w_ih_f, w_hh_f, w_ih_b, w_hh_b, wl_hi, wl_lo);

    // ---- bidirectional LSTM, 16 sequential steps (split-K x2) ----
    for (int t = 0; t < 16; ++t) {
        gemm_lstm_g<<<dim3(4, 16, 4), dim3(256), 0, stream>>>(
            t, lens, x_hi, x_lo, hc_hi, hc_lo, wl_hi, wl_lo, gbuf);
        lstm_gate<<<dim3(NB, 2), dim3(256), 0, stream>>>(
            t, lens, b_f, b_b, gbuf, ccur, hc_hi, hc_lo, h_hi, h_lo, c_seq);
    }

    // ---- iter 0: candidates + logits (length-compacted if vbuf fits) ----
    if (chunk >= NPAIR0) {
        gemm_pairs_g<128, 2048><<<dim3(30, 40, 1), dim3(256), 0, stream>>>(
            rowlist_c, NPAIR0, (const int*)(rcount + 14), 0,
            h_hi, h_lo, w_hi, w_lo, vbuf);
        gates_logits<<<dim3(NPAIR0), dim3(256), 0, stream>>>(
            rowlist_c, NPAIR0, (const int*)(rcount + 14),
            vbuf, 0, 1, b_comp, c_seq, w_q, nh, nc, logits);
    } else {
        for (int off = 0; off < NPAIR0; off += chunk) {
            int rows = NPAIR0 - off; if (rows > chunk) rows = chunk;
            int RT = (rows + 127) >> 7;
            gemm_pairs_g<128, 2048><<<dim3(RT, 40, 1), dim3(256), 0, stream>>>(
                rowlist0 + off, rows, (const int*)nullptr, 0,
                h_hi, h_lo, w_hi, w_lo, vbuf);
            gates_logits<<<dim3(rows), dim3(256), 0, stream>>>(
                rowlist0 + off, rows, (const int*)nullptr,
                vbuf, 0, 1, b_comp, c_seq, w_q, nh, nc, logits);
        }
    }

    // ---- 14 selection iterations (compacted incremental, split-K x4) ----
    for (int it = 0; it < 14; ++it) {
        merge_kernel<<<dim3(NB), dim3(256), 0, stream>>>(
            it, lens, c_seq, nh, nc, logits, pos, pair,
            rowlist_inc, rcount + it, h_hi, h_lo);
        gemm_pairs_g<128, 512><<<dim3(4, 40, 4), dim3(256), 0, stream>>>(
            rowlist_inc, 0, (const int*)(rcount + it), INC_CAP,
            h_hi, h_lo, w_hi, w_lo, vbuf);
        gates_logits<<<dim3(INC_CAP), dim3(256), 0, stream>>>(
            rowlist_inc, 0, (const int*)(rcount + it),
            vbuf, INC_CAP, 4, b_comp, c_seq, w_q, nh, nc, logits);
    }
    merge_kernel<<<dim3(NB), dim3(256), 0, stream>>>(
        14, lens, c_seq, nh, nc, logits, pos, pair,
        rowlist_inc, rcount + 15, h_hi, h_lo);

    copy_out<<<dim3(NB), dim3(256), 0, stream>>>(h_hi, h_lo, out);
}